// Round 3
// baseline (1714.911 us; speedup 1.0000x reference)
//
#include <hip/hip_runtime.h>

// JIIF fused pipeline v12 = v11 with expand_a1 PRODUCER-FUSED into layer-2.
//   gemm_l12: BM=128 x BN=256, BK=64, 512 thr / 8 waves (2M x 4N, 64x64 each).
//   A-tile (= A1 rows) is CONSTRUCTED in-kernel: per thread 2 rows x 8 cols:
//   relu(b1 + Yhr[p] + mask*Ycell[cell] + ry*w1rel0 + rx*w1rel1) -> swizzled
//   ds_write. A1 never touches HBM; chunk bytes/pixel 14336->6144 -> nc 16->4.
//   Schedule: 2 phases/K-tile (k-halves), ONE s_barrier per tile (end P1).
//   B triple-buffered (staged 2 tiles ahead via global_load_lds); A double-
//   buffered (constructed 1 tile ahead). Steady gate: single vmcnt(2) at P1
//   start; oldest-first retirement => it forces exactly {B(t+1) 4, aloads 10}
//   and leaves B0(t+2) 2 in flight, independent of intra-tile load reorder.
//   lgkmcnt(0) before the tile barrier publishes A ds_writes + frag reads.
//   Registers: acc 4x4 f32x4 = 64 (AGPR) + ~40 transient load regs fits the
//   256/wave budget for 2 waves/SIMD (256^2 variant would not: 128 AGPR).
// NOTES:
//  - R1(v10): 2-barrier 8-phase = null (52.7us) -> barrier count was the
//    blocker, not phase count. R2(v11): 1-barrier/phase quadrant 256^2 ->
//    gemm 52.7 -> <39.6us. v12 keeps the 1-barrier principle.
//  - R4/R5 (prev session): 512-thread fused tail spilled; tail34 stays 256t.
//  - ws_size = 256 MiB (268.4MB fills in R2 profile) -> nc=4 only possible
//    because A1 (8KB/pixel) is gone.

typedef unsigned short u16;
typedef unsigned int   u32;
typedef __bf16  bf16x8 __attribute__((ext_vector_type(8)));
typedef float   f32x4  __attribute__((ext_vector_type(4)));
typedef unsigned short u16x8 __attribute__((ext_vector_type(8)));

__device__ __forceinline__ u16 f2bf(float f) {
  u32 u = __float_as_uint(f);
  u32 r = (u + 0x7FFFu + ((u >> 16) & 1u)) >> 16;   // RNE
  return (u16)r;
}
__device__ __forceinline__ float bf2f(u16 v) {
  return __uint_as_float(((u32)v) << 16);
}
__device__ __forceinline__ void gload_lds16(const void* g, void* l) {
  __builtin_amdgcn_global_load_lds(
      (const __attribute__((address_space(1))) void*)g,
      (__attribute__((address_space(3))) void*)l, 16, 0, 0);
}

// ---------------------------------------------------------------------------
// gather_hr: per-pixel Xhr row (q_guide_hr, bf16[128]) + cellidx[pix][4] + rel[pix][4][2]
// ---------------------------------------------------------------------------
__global__ __launch_bounds__(256)
void gather_hr(const float* __restrict__ coord, const float* __restrict__ hr,
               u16* __restrict__ Xhr, int* __restrict__ cellidx, float* __restrict__ rel)
{
  __shared__ u16 hrT[64 * 130];
  __shared__ int nhrS[64];

  const int tid = threadIdx.x;
  const int pb  = blockIdx.x << 6;        // global pixel base
  const int b   = pb >> 16;
  const int n0  = pb & 65535;
  const float rh = 0.015625f;             // 1/64

  if (tid < 64) {
    const int n = n0 + tid;
    const float cy = coord[(size_t)(b * 65536 + n) * 2 + 0];
    const float cx = coord[(size_t)(b * 65536 + n) * 2 + 1];
    float fyh = (cy + 1.0f) * 128.0f - 0.5f;
    float fxh = (cx + 1.0f) * 128.0f - 0.5f;
    int iyh = (int)floorf(fyh + 0.5f);
    int ixh = (int)floorf(fxh + 0.5f);
    bool vh = (iyh >= 0 && iyh < 256 && ixh >= 0 && ixh < 256);
    nhrS[tid] = vh ? ((iyh << 8) + ixh) : -1;
#pragma unroll
    for (int k = 0; k < 4; ++k) {
      const float vx = (k < 2) ? -1.0f : 1.0f;
      const float vy = (k & 1) ? 1.0f : -1.0f;
      const float cyk = cy + vx * rh;
      const float cxk = cx + vy * rh;
      float fy = (cyk + 1.0f) * 32.0f - 0.5f;
      float fx = (cxk + 1.0f) * 32.0f - 0.5f;
      int iy = (int)floorf(fy + 0.5f);
      int ix = (int)floorf(fx + 0.5f);
      bool valid = (iy >= 0 && iy < 64 && ix >= 0 && ix < 64);
      int iyc = min(max(iy, 0), 63);
      int ixc = min(max(ix, 0), 63);
      float qy = valid ? ((-1.0f + rh) + (2.0f * rh) * (float)iyc) : 0.0f;
      float qx = valid ? ((-1.0f + rh) + (2.0f * rh) * (float)ixc) : 0.0f;
      const int p4 = ((pb + tid) << 2) + k;
      rel[2 * p4 + 0] = (cy - qy) * 64.0f;
      rel[2 * p4 + 1] = (cx - qx) * 64.0f;
      cellidx[p4] = valid ? (b * 4096 + iyc * 64 + ixc) : -1;
    }
  }
  __syncthreads();

  const size_t hb = (size_t)b * 128 * 65536;
  for (int e = tid; e < 64 * 128; e += 256) {
    const int pix = e & 63, c = e >> 6;
    const int n = nhrS[pix];
    const float v = (n >= 0) ? hr[hb + (size_t)c * 65536 + n] : 0.0f;
    hrT[pix * 130 + c] = f2bf(v);
  }
  __syncthreads();

  for (int e = tid; e < 64 * 128; e += 256) {
    const int pix = e >> 7, c = e & 127;
    Xhr[(size_t)(pb + pix) * 128 + c] = hrT[pix * 130 + c];
  }
}

// ---------------------------------------------------------------------------
// prep_cells: Xcell[cell][0:128]=feat, [128:256]=-lr  (bf16)
// ---------------------------------------------------------------------------
__global__ __launch_bounds__(256)
void prep_cells(const float* __restrict__ feat, const float* __restrict__ lr,
                u16* __restrict__ Xcell)
{
  __shared__ u16 t[64 * 258];
  const int tid = threadIdx.x;
  const int cb = blockIdx.x << 6;
  const int b = cb >> 12;
  const int local = cb & 4095;
  const size_t fb = (size_t)b * 128 * 4096;
  for (int e = tid; e < 64 * 128; e += 256) {
    const int cell = e & 63, c = e >> 6;
    const size_t idx = fb + (size_t)c * 4096 + local + cell;
    t[cell * 258 + c]       = f2bf(feat[idx]);
    t[cell * 258 + 128 + c] = (u16)(f2bf(lr[idx]) ^ 0x8000u);
  }
  __syncthreads();
  for (int e = tid; e < 64 * 256; e += 256) {
    const int cell = e >> 8, c = e & 255;
    Xcell[(size_t)(cb + cell) * 256 + c] = t[cell * 258 + c];
  }
}

// ---------------------------------------------------------------------------
// bf16 MFMA GEMM; BK=64 via two 32-k LDS slabs; 128x128 tile.
// MODE 0: C bf16 = relu(A@B^T + bias);  MODE 3: C bf16 = A@B^T (raw)
// (kept for Ycell / Yhr GEMMs where K is short: 256 / 128)
// ---------------------------------------------------------------------------
template<int MODE>
__global__ __launch_bounds__(256)
void gemm_bt(const u16* __restrict__ A, const u16* __restrict__ BT,
             void* __restrict__ Cout, const float* __restrict__ bias,
             int M, int N, int K)
{
  __shared__ __align__(16) u16 sh[16384];
  u16* As = sh;
  u16* Bs = sh + 8192;

  const int tid = threadIdx.x;
  const int w = tid >> 6;
  const int lane = tid & 63;
  const int ntn = N >> 7;
  const int nmt = M >> 7;
  int bm, bn;
  if ((nmt & 7) == 0) {
    const int xcd = blockIdx.x & 7;
    const int t = blockIdx.x >> 3;
    bn = t % ntn;
    bm = xcd * (nmt >> 3) + t / ntn;
  } else {
    bm = blockIdx.x / ntn;
    bn = blockIdx.x - bm * ntn;
  }
  const int m0 = bm << 7, n0 = bn << 7;

  const int lrow = tid >> 2;
  const int cc   = tid & 3;
  const int gcol = (cc ^ ((lrow >> 1) & 3)) << 3;

  f32x4 acc[4][4];
#pragma unroll
  for (int ii = 0; ii < 4; ++ii)
#pragma unroll
    for (int jj = 0; jj < 4; ++jj)
      acc[ii][jj] = f32x4{0.f, 0.f, 0.f, 0.f};

  const int mbase = (w & 1) << 6;
  const int nbase = (w >> 1) << 6;
  const int fr = lane & 15;
  const int fq = lane >> 4;
  const int rchunk = (fq ^ ((fr >> 1) & 3)) << 3;

  for (int kt = 0; kt < K; kt += 64) {
#pragma unroll
    for (int s = 0; s < 2; ++s) {
      const int kb = kt + (s << 5);
#pragma unroll
      for (int q = 0; q < 2; ++q) {
        const int mrow = (q << 6) + lrow;
        gload_lds16(A + (size_t)(m0 + mrow) * K + (kb + gcol),
                    (char*)As + (s << 13) + (q << 12) + (w << 10));
        gload_lds16(BT + (size_t)(n0 + mrow) * K + (kb + gcol),
                    (char*)Bs + (s << 13) + (q << 12) + (w << 10));
      }
    }
    __syncthreads();
#pragma unroll
    for (int s = 0; s < 2; ++s) {
      const int so = s << 12;
      bf16x8 af[4], bfv[4];
#pragma unroll
      for (int ii = 0; ii < 4; ++ii) {
        af[ii]  = *(const bf16x8*)(As + so + ((mbase + (ii << 4) + fr) << 5) + rchunk);
        bfv[ii] = *(const bf16x8*)(Bs + so + ((nbase + (ii << 4) + fr) << 5) + rchunk);
      }
#pragma unroll
      for (int ii = 0; ii < 4; ++ii)
#pragma unroll
        for (int jj = 0; jj < 4; ++jj)
          acc[ii][jj] = __builtin_amdgcn_mfma_f32_16x16x32_bf16(af[ii], bfv[jj], acc[ii][jj], 0, 0, 0);
    }
    __syncthreads();
  }

#pragma unroll
  for (int jj = 0; jj < 4; ++jj) {
    const int ncol = n0 + nbase + (jj << 4) + fr;
    const float bi = (MODE == 0) ? bias[ncol] : 0.f;
#pragma unroll
    for (int ii = 0; ii < 4; ++ii) {
#pragma unroll
      for (int r = 0; r < 4; ++r) {
        const int mrow = m0 + mbase + (ii << 4) + (fq << 2) + r;
        if (MODE == 0) {
          ((u16*)Cout)[(size_t)mrow * N + ncol] = f2bf(fmaxf(acc[ii][jj][r] + bi, 0.f));
        } else {
          ((u16*)Cout)[(size_t)mrow * N + ncol] = f2bf(acc[ii][jj][r]);
        }
      }
    }
  }
}

// ---------------------------------------------------------------------------
// gemm_l12: fused expand(layer-1 combine) + layer-2 GEMM.
//   C = relu(A1 @ W2T^T + b2), where A1 row rr (pixel p=rr>>2, branch k=rr&3)
//   is constructed on the fly:
//     A1[rr][c] = relu(b1[c] + Yhr[p][c] + mask*Ycell[cell[p][k]][c]
//                      + ry*w1rel[0][c] + rx*w1rel[1][c])
//   BM=128, BN=256, BK=64, 512 threads / 8 waves (wm=w>>2 rows, wn=w&3 cols).
//   LDS 128KB: A 2buf x [128][64] @u16 0/8192; B 3buf x [256][64] @u16
//   16384+q*16384. 8-wide XOR chunk swizzle on both (chunk c holds global
//   chunk c^(row&7)).
//   Per tile: P0 {frags ks0; issue 10 A-loads(t+1); DMA-stage B0(t+2); 16
//   MFMA} P1 {frags ks1; vmcnt(2); construct+ds_write A(t+1); stage B1(t+2);
//   lgkmcnt(0); s_barrier; 16 MFMA}. One barrier/tile.
// ---------------------------------------------------------------------------
__global__ __launch_bounds__(512, 2)
void gemm_l12(const u16* __restrict__ Yhr, const u16* __restrict__ Ycell,
              const float* __restrict__ b1, const float* __restrict__ w1rel,
              const int* __restrict__ cellidx, const float* __restrict__ rel,
              const u16* __restrict__ BT, u16* __restrict__ Cout,
              const float* __restrict__ bias, int M, int N, int K, int gp0)
{
  __shared__ __align__(16) u16 sh[65536];   // 128 KB
  char* shb = (char*)sh;

  const int tid  = threadIdx.x;
  const int w    = tid >> 6;
  const int lane = tid & 63;
  const int wm = w >> 2, wn = w & 3;
  const int ntn = N >> 8;                   // 2
  const int nmt = M >> 7;
  const int nwg = ntn * nmt;
  int bid = blockIdx.x;
  if ((nwg & 7) == 0) {
    const int cpx = nwg >> 3;
    bid = (bid & 7) * cpx + (bid >> 3);     // bijective XCD swizzle
  }
  const int bm = bid / ntn, bn = bid % ntn;
  const int m0 = bm << 7, n0 = bn << 8;
  const int NT = K >> 6;

  // staging/construction thread mapping
  const int srow = tid >> 3;                // 0..63
  const int cg   = tid & 7;
  const int gk   = (cg ^ (srow & 7)) << 3;  // swizzled source k offset (u16)
  const int swz8 = (cg ^ (srow & 7)) << 3;  // swizzled LDS chunk (u16)

  // fragment mapping
  const int fr = lane & 15;
  const int fq = lane >> 4;
  const int pk0 = ((fq)     ^ (fr & 7)) << 3;
  const int pk1 = ((4 + fq) ^ (fr & 7)) << 3;
  const int awr = (wm << 6) + fr;           // A frag row base
  const int bwr = (wn << 6) + fr;           // B frag row base

  // per-row persistent gather state (2 rows/thread: rr = srow, 64+srow)
  const int m04 = m0 >> 2;
  const int kk  = srow & 3;
  const int pA  = m04 + (srow >> 2);
  const int pB  = pA + 16;
  const int idxA = (gp0 + pA) * 4 + kk;
  const int idxB = (gp0 + pB) * 4 + kk;
  const int cellA = cellidx[idxA];
  const int cellB = cellidx[idxB];
  const float2 rvA = *(const float2*)(rel + (size_t)idxA * 2);
  const float2 rvB = *(const float2*)(rel + (size_t)idxB * 2);
  const float ryA = rvA.x, rxA = rvA.y, ryB = rvB.x, rxB = rvB.y;
  const u16 mkA = (u16)(cellA >= 0 ? 0xFFFFu : 0u);
  const u16 mkB = (u16)(cellB >= 0 ? 0xFFFFu : 0u);
  const u16x8 mskA = {mkA, mkA, mkA, mkA, mkA, mkA, mkA, mkA};
  const u16x8 mskB = {mkB, mkB, mkB, mkB, mkB, mkB, mkB, mkB};
  const u16* yA = Yhr + (size_t)pA * 1024;
  const u16* yB = Yhr + (size_t)pB * 1024;
  const u16* zA = Ycell + (size_t)max(cellA, 0) * 1024;
  const u16* zB = Ycell + (size_t)max(cellB, 0) * 1024;

  u16x8 yhA, yhB, ycA, ycB;
  float4 c_b0, c_b1, c_w00, c_w01, c_w10, c_w11;

#define A_LOADS(kt1_) do { const int co_ = (kt1_) + (cg << 3); \
    yhA = *(const u16x8*)(yA + co_); yhB = *(const u16x8*)(yB + co_); \
    ycA = *(const u16x8*)(zA + co_); ycB = *(const u16x8*)(zB + co_); \
    c_b0  = *(const float4*)(b1 + co_);            c_b1  = *(const float4*)(b1 + co_ + 4); \
    c_w00 = *(const float4*)(w1rel + co_);         c_w01 = *(const float4*)(w1rel + co_ + 4); \
    c_w10 = *(const float4*)(w1rel + 1024 + co_);  c_w11 = *(const float4*)(w1rel + 1024 + co_ + 4); } while (0)

#define A_CONS(ab_) do { \
    const u16x8 za_ = ycA & mskA, zb_ = ycB & mskB; \
    const float bb_[8]  = {c_b0.x, c_b0.y, c_b0.z, c_b0.w, c_b1.x, c_b1.y, c_b1.z, c_b1.w}; \
    const float w0_[8]  = {c_w00.x, c_w00.y, c_w00.z, c_w00.w, c_w01.x, c_w01.y, c_w01.z, c_w01.w}; \
    const float w1_[8]  = {c_w10.x, c_w10.y, c_w10.z, c_w10.w, c_w11.x, c_w11.y, c_w11.z, c_w11.w}; \
    u16x8 oA_, oB_; \
    _Pragma("unroll") \
    for (int j_ = 0; j_ < 8; ++j_) { \
      const float bs_ = bb_[j_], f0_ = w0_[j_], f1_ = w1_[j_]; \
      float vA_ = bs_ + bf2f(yhA[j_]) + bf2f(za_[j_]) + ryA * f0_ + rxA * f1_; \
      float vB_ = bs_ + bf2f(yhB[j_]) + bf2f(zb_[j_]) + ryB * f0_ + rxB * f1_; \
      oA_[j_] = f2bf(fmaxf(vA_, 0.f)); \
      oB_[j_] = f2bf(fmaxf(vB_, 0.f)); \
    } \
    *(u16x8*)(sh + (ab_) + (srow << 6) + swz8) = oA_; \
    *(u16x8*)(sh + (ab_) + ((64 + srow) << 6) + swz8) = oB_; } while (0)

#define STAGE_B(q_, h_, kt_) do { \
    gload_lds16(BT + (size_t)(n0 + ((h_) << 7) + srow) * K + (kt_) + gk, \
                shb + 32768 + ((q_) << 15) + ((h_) << 14) + (w << 10)); \
    gload_lds16(BT + (size_t)(n0 + ((h_) << 7) + 64 + srow) * K + (kt_) + gk, \
                shb + 32768 + ((q_) << 15) + ((h_) << 14) + 8192 + (w << 10)); } while (0)
#define BAR12()   asm volatile("s_barrier" ::: "memory")
#define VMC(n)    asm volatile("s_waitcnt vmcnt(" #n ")" ::: "memory")
#define LGKM0_()  asm volatile("s_waitcnt lgkmcnt(0)" ::: "memory")

  f32x4 acc[4][4];
#pragma unroll
  for (int i = 0; i < 4; ++i)
#pragma unroll
    for (int j = 0; j < 4; ++j)
      acc[i][j] = f32x4{0.f, 0.f, 0.f, 0.f};

  // ---- prologue: construct A(0) -> Abuf0; stage B(0)->q0, B(1)->q1 ----
  A_LOADS(0);
  VMC(0);
  A_CONS(0);
  STAGE_B(0, 0, 0);
  STAGE_B(0, 1, 0);
  if (NT > 1) { STAGE_B(1, 0, 64); STAGE_B(1, 1, 64); }
  VMC(0);          // one-time full drain (safe vs any stage reorder)
  LGKM0_();
  BAR12();

  for (int t = 0; t < NT; ++t) {
    const int Ab = (t & 1) << 13;                 // u16 offset of A buf
    const int Bb = 16384 + ((t % 3) << 14);       // u16 offset of B buf
    const bool mA_ = (t + 1 < NT);
    const bool mB_ = (t + 2 < NT);
    const int kt1 = (t + 1) << 6;
    const int kt2 = (t + 2) << 6;
    const int q2 = (t + 2) % 3;

    // ---- P0: k-slice 0 ----
    bf16x8 a0[4], g0[4];
#pragma unroll
    for (int i = 0; i < 4; ++i)
      a0[i] = *(const bf16x8*)(sh + Ab + ((awr + (i << 4)) << 6) + pk0);
#pragma unroll
    for (int j = 0; j < 4; ++j)
      g0[j] = *(const bf16x8*)(sh + Bb + ((bwr + (j << 4)) << 6) + pk0);
    if (mA_) A_LOADS(kt1);
    if (mB_) STAGE_B(q2, 0, kt2);
    __builtin_amdgcn_s_setprio(1);
#pragma unroll
    for (int i = 0; i < 4; ++i)
#pragma unroll
      for (int j = 0; j < 4; ++j)
        acc[i][j] = __builtin_amdgcn_mfma_f32_16x16x32_bf16(a0[i], g0[j], acc[i][j], 0, 0, 0);
    __builtin_amdgcn_s_setprio(0);

    // ---- P1: k-slice 1 ----
    bf16x8 a1[4], g1[4];
#pragma unroll
    for (int i = 0; i < 4; ++i)
      a1[i] = *(const bf16x8*)(sh + Ab + ((awr + (i << 4)) << 6) + pk1);
#pragma unroll
    for (int j = 0; j < 4; ++j)
      g1[j] = *(const bf16x8*)(sh + Bb + ((bwr + (j << 4)) << 6) + pk1);
    if (mA_) {
      if (mB_) VMC(2); else VMC(0);   // forces B(t+1) + A-loads(t+1)
      A_CONS(((t + 1) & 1) << 13);
    }
    if (mB_) STAGE_B(q2, 1, kt2);
    LGKM0_();
    BAR12();
    __builtin_amdgcn_s_setprio(1);
#pragma unroll
    for (int i = 0; i < 4; ++i)
#pragma unroll
      for (int j = 0; j < 4; ++j)
        acc[i][j] = __builtin_amdgcn_mfma_f32_16x16x32_bf16(a1[i], g1[j], acc[i][j], 0, 0, 0);
    __builtin_amdgcn_s_setprio(0);
  }

#undef A_LOADS
#undef A_CONS
#undef STAGE_B
#undef BAR12
#undef VMC
#undef LGKM0_

  // ---- epilogue: relu(acc + bias) -> bf16 ----
#pragma unroll
  for (int j = 0; j < 4; ++j) {
    const int ncol = n0 + (wn << 6) + (j << 4) + fr;
    const float bi = bias[ncol];
#pragma unroll
    for (int i = 0; i < 4; ++i) {
#pragma unroll
      for (int r = 0; r < 4; ++r) {
        const int mrow = m0 + (wm << 6) + (i << 4) + (fq << 2) + r;
        Cout[(size_t)mrow * N + ncol] = f2bf(fmaxf(acc[i][j][r] + bi, 0.f));
      }
    }
  }
}

// ---------------------------------------------------------------------------
// tail34: layers 3+4+5 for a 64-row block (16 pixels), 256 threads / 4 waves.
// ---------------------------------------------------------------------------
__global__ __launch_bounds__(256)
void tail34(const u16* __restrict__ A2, const u16* __restrict__ W3T,
            const u16* __restrict__ W4T, const float* __restrict__ b3,
            const float* __restrict__ b4, const float* __restrict__ w5,
            const float* __restrict__ b5, float* __restrict__ outp,
            int M, int gp0)
{
  __shared__ __align__(16) u16 sh[24576];   // 48 KB
  u16* As  = sh;            // L3 A staging: 2 slabs x (64x32)   [0,4096) u16
  u16* Bs  = sh + 4096;     // L3 B staging: 2 slabs x (256x32)  [4096,20480) u16
  u16* A3s = sh;            // A3 slabs: 8 x (64x32) [0,16384) u16 (aliases As/Bs)
  u16* W4s = sh + 16384;    // W4 staging: 2 slabs x (128x32) [16384,24576) u16
  // blend tile 64x136 aliases sh[0,8704) after layer-4.

  const int tid = threadIdx.x;
  const int w = tid >> 6;
  const int lane = tid & 63;
  const int nmt = M >> 6;
  int bm;
  if ((nmt & 7) == 0) bm = (blockIdx.x & 7) * (nmt >> 3) + (blockIdx.x >> 3);
  else bm = blockIdx.x;
  const int m0 = bm << 6;

  const int lrow = tid >> 2;                 // 0..63
  const int cc   = tid & 3;
  const int gcol = (cc ^ ((lrow >> 1) & 3)) << 3;

  const int fr = lane & 15;
  const int fq = lane >> 4;
  const int rchunk = (fq ^ ((fr >> 1) & 3)) << 3;
  const int nb3 = w << 6;                    // layer-3 wave col base

  // ---------------- layer-3 (M-tile 64, N 256, K 512) ----------------
  f32x4 acc3[4][4];
#pragma unroll
  for (int ii = 0; ii < 4; ++ii)
#pragma unroll
    for (int jj = 0; jj < 4; ++jj)
      acc3[ii][jj] = f32x4{0.f, 0.f, 0.f, 0.f};

  for (int kt = 0; kt < 512; kt += 64) {
#pragma unroll
    for (int s = 0; s < 2; ++s) {
      const int kb = kt + (s << 5);
      gload_lds16(A2 + (size_t)(m0 + lrow) * 512 + (kb + gcol),
                  (char*)As + (s << 12) + (w << 10));
#pragma unroll
      for (int q = 0; q < 4; ++q) {
        gload_lds16(W3T + (size_t)((q << 6) + lrow) * 512 + (kb + gcol),
                    (char*)Bs + (s << 14) + (q << 12) + (w << 10));
      }
    }
    __syncthreads();
#pragma unroll
    for (int s = 0; s < 2; ++s) {
      bf16x8 af[4], bfv[4];
#pragma unroll
      for (int ii = 0; ii < 4; ++ii) {
        af[ii]  = *(const bf16x8*)(As + (s << 11) + (((ii << 4) + fr) << 5) + rchunk);
        bfv[ii] = *(const bf16x8*)(Bs + (s << 13) + ((nb3 + (ii << 4) + fr) << 5) + rchunk);
      }
#pragma unroll
      for (int ii = 0; ii < 4; ++ii)
#pragma unroll
        for (int jj = 0; jj < 4; ++jj)
          acc3[ii][jj] = __builtin_amdgcn_mfma_f32_16x16x32_bf16(af[ii], bfv[jj], acc3[ii][jj], 0, 0, 0);
    }
    __syncthreads();
  }

  // ---------------- funnel: A3 = relu(acc3+b3) -> swizzled LDS slabs -------
  float b3v[4];
#pragma unroll
  for (int jj = 0; jj < 4; ++jj) b3v[jj] = b3[nb3 + (jj << 4) + fr];
#pragma unroll
  for (int jj = 0; jj < 4; ++jj) {
    const int col = nb3 + (jj << 4) + fr;
    const int sl = col >> 5, c = col & 31;
#pragma unroll
    for (int ii = 0; ii < 4; ++ii) {
#pragma unroll
      for (int r = 0; r < 4; ++r) {
        const int row = (ii << 4) + (fq << 2) + r;
        A3s[(sl << 11) + (row << 5) + (((c >> 3) ^ ((row >> 1) & 3)) << 3) + (c & 7)] =
            f2bf(fmaxf(acc3[ii][jj][r] + b3v[jj], 0.f));
      }
    }
  }

  // ---------------- layer-4 (K=256 from A3 slabs; N=128) ----------------
  f32x4 acc4[4][2];
#pragma unroll
  for (int ii = 0; ii < 4; ++ii)
#pragma unroll
    for (int jj = 0; jj < 2; ++jj)
      acc4[ii][jj] = f32x4{0.f, 0.f, 0.f, 0.f};
  const int nb4 = w << 5;

  for (int kt4 = 0; kt4 < 4; ++kt4) {
#pragma unroll
    for (int s = 0; s < 2; ++s) {
      const int kb = (kt4 << 6) + (s << 5);
#pragma unroll
      for (int q = 0; q < 2; ++q) {
        gload_lds16(W4T + (size_t)((q << 6) + lrow) * 256 + (kb + gcol),
                    (char*)W4s + (s << 13) + (q << 12) + (w << 10));
      }
    }
    __syncthreads();   // W4 visible; first iter also publishes the A3 funnel
#pragma unroll
    for (int s = 0; s < 2; ++s) {
      const int sl = (kt4 << 1) + s;
      bf16x8 af[4], bfv[2];
#pragma unroll
      for (int ii = 0; ii < 4; ++ii)
        af[ii] = *(const bf16x8*)(A3s + (sl << 11) + (((ii << 4) + fr) << 5) + rchunk);
#pragma unroll
      for (int jj = 0; jj < 2; ++jj)
        bfv[jj] = *(const bf16x8*)(W4s + (s << 12) + ((nb4 + (jj << 4) + fr) << 5) + rchunk);
#pragma unroll
      for (int ii = 0; ii < 4; ++ii)
#pragma unroll
        for (int jj = 0; jj < 2; ++jj)
          acc4[ii][jj] = __builtin_amdgcn_mfma_f32_16x16x32_bf16(af[ii], bfv[jj], acc4[ii][jj], 0, 0, 0);
    }
    __syncthreads();
  }

  // ---------------- layer-5 + softmax blend ----------------
  float b4v[2];
#pragma unroll
  for (int jj = 0; jj < 2; ++jj) b4v[jj] = b4[nb4 + (jj << 4) + fr];
#pragma unroll
  for (int ii = 0; ii < 4; ++ii) {
#pragma unroll
    for (int jj = 0; jj < 2; ++jj) {
      const int col = nb4 + (jj << 4) + fr;
#pragma unroll
      for (int r = 0; r < 4; ++r) {
        const int row = (ii << 4) + (fq << 2) + r;
        sh[row * 136 + col] = f2bf(fmaxf(acc4[ii][jj][r] + b4v[jj], 0.f));
      }
    }
  }
  const int cbase = fr << 3;
  float w50[8], w51[8];
#pragma unroll
  for (int j = 0; j < 8; ++j) {
    w50[j] = w5[((cbase + j) << 1) + 0];
    w51[j] = w5[((cbase + j) << 1) + 1];
  }
  const float b50 = b5[0], b51 = b5[1];
  __syncthreads();

#pragma unroll
  for (int rep = 0; rep < 4; ++rep) {
    const int pl = (rep << 2) + w;            // block-local pixel 0..15
    const int row = (pl << 2) + fq;           // branch k = fq
    const u16x8 v = *(const u16x8*)(sh + row * 136 + cbase);
    float s0 = 0.f, s1 = 0.f;
#pragma unroll
    for (int j = 0; j < 8; ++j) {
      const float a = bf2f(v[j]);
      s0 += a * w50[j];
      s1 += a * w51[j];
    }
#pragma unroll
    for (int off = 8; off >= 1; off >>= 1) {
      s0 += __shfl_xor(s0, off, 16);
      s1 += __shfl_xor(s1, off, 16);
    }
    float p0[4], p1[4];
#pragma unroll
    for (int k = 0; k < 4; ++k) {
      p0[k] = __shfl(s0, k << 4, 64) + b50;
      p1[k] = __shfl(s1, k << 4, 64) + b51;
    }
    if (lane == 0) {
      float mx = fmaxf(fmaxf(p1[0], p1[1]), fmaxf(p1[2], p1[3]));
      float e0 = expf(p1[0] - mx), e1 = expf(p1[1] - mx);
      float e2 = expf(p1[2] - mx), e3 = expf(p1[3] - mx);
      outp[gp0 + (m0 >> 2) + pl] =
          (p0[0] * e0 + p0[1] * e1 + p0[2] * e2 + p0[3] * e3) / (e0 + e1 + e2 + e3);
    }
  }
}

// ---------------------------------------------------------------------------
// prep_all: all transposed bf16 weights in one dispatch.
// ---------------------------------------------------------------------------
__global__ __launch_bounds__(256)
void prep_all(const float* __restrict__ w1, const float* __restrict__ w2,
              const float* __restrict__ w3, const float* __restrict__ w4,
              u16* __restrict__ W1hrT, u16* __restrict__ W1cellT,
              u16* __restrict__ W2T, u16* __restrict__ W3T, u16* __restrict__ W4T)
{
  const int idx = blockIdx.x * 256 + threadIdx.x;
  if (idx < 131072) {
    const int n = idx >> 7, k = idx & 127;
    W1hrT[idx] = f2bf(w1[(128 + k) * 1024 + n] + w1[(256 + k) * 1024 + n]);
  } else if (idx < 393216) {
    const int i = idx - 131072;
    const int n = i >> 8, k = i & 255;
    W1cellT[i] = f2bf((k < 128) ? w1[k * 1024 + n] : w1[(128 + k) * 1024 + n]);
  } else if (idx < 917504) {
    const int i = idx - 393216;
    const int n = i >> 10, k = i & 1023;
    W2T[i] = f2bf(w2[k * 512 + n]);
  } else if (idx < 1048576) {
    const int i = idx - 917504;
    const int n = i >> 9, k = i & 511;
    W3T[i] = f2bf(w3[k * 256 + n]);
  } else if (idx < 1081344) {
    const int i = idx - 1048576;
    const int n = i >> 8, k = i & 255;
    W4T[i] = f2bf(w4[k * 128 + n]);
  }
}

// ---------------------------------------------------------------------------
extern "C" void kernel_launch(void* const* d_in, const int* in_sizes, int n_in,
                              void* d_out, int out_size, void* d_ws, size_t ws_size,
                              hipStream_t stream)
{
  const float* feat  = (const float*)d_in[0];
  const float* coord = (const float*)d_in[1];
  const float* hrg   = (const float*)d_in[2];
  const float* lrg   = (const float*)d_in[3];
  const float* w1 = (const float*)d_in[4];
  const float* b1 = (const float*)d_in[5];
  const float* w2 = (const float*)d_in[6];
  const float* b2 = (const float*)d_in[7];
  const float* w3 = (const float*)d_in[8];
  const float* b3 = (const float*)d_in[9];
  const float* w4 = (const float*)d_in[10];
  const float* b4 = (const float*)d_in[11];
  const float* w5 = (const float*)d_in[12];
  const float* b5 = (const float*)d_in[13];
  float* out = (float*)d_out;

  char* base = (char*)d_ws;
  u16* W1hrT   = (u16*)base;                       // [1024][128]
  u16* W1cellT = W1hrT + 1024 * 128;               // [1024][256]
  u16* W2T     = W1cellT + 1024 * 256;             // [512][1024]
  u16* W3T     = W2T + 512 * 1024;                 // [256][512]
  u16* W4T     = W3T + 256 * 512;                  // [128][256]
  u16* Xcell   = W4T + 128 * 256;                  // [8192][256]
  u16* Ycell   = Xcell + 8192 * 256;               // [8192][1024] bf16
  u16* Xhr     = Ycell + (size_t)8192 * 1024;      // [131072][128]
  float* relb  = (float*)(Xhr + (size_t)131072 * 128); // [131072][4][2]
  int* cellidx = (int*)(relb + (size_t)131072 * 8);    // [131072][4]
  char* chunk_base = (char*)(cellidx + (size_t)131072 * 4);
  const size_t fixed = (size_t)(chunk_base - base);

  const int NP = 131072;
  // per-pixel chunk bytes: Yhr 2048 + A2 4096 = 6144 (A1 fused away)
  int nc = 1;
  while (nc < 128 && fixed + (size_t)(NP / nc) * 6144ULL > ws_size) nc <<= 1;
  const int CP = NP / nc;
  const int R = CP * 4;

  u16* Yhr = (u16*)chunk_base;          // [CP][1024] bf16
  u16* A2  = Yhr + (size_t)CP * 1024;   // [R][512] bf16

  prep_all<<<4224, 256, 0, stream>>>(w1, w2, w3, w4, W1hrT, W1cellT, W2T, W3T, W4T);
  gather_hr<<<NP / 64, 256, 0, stream>>>(coord, hrg, Xhr, cellidx, relb);
  prep_cells<<<8192 / 64, 256, 0, stream>>>(feat, lrg, Xcell);
  // Ycell = Xcell @ W1cellT^T (raw bf16)
  gemm_bt<3><<<(8192 / 128) * (1024 / 128), 256, 0, stream>>>(
      Xcell, W1cellT, (void*)Ycell, nullptr, 8192, 1024, 256);

  for (int ch = 0; ch < nc; ++ch) {
    const int gp0 = ch * CP;
    // Yhr = Xhr_chunk @ W1hrT^T (raw bf16)
    gemm_bt<3><<<(CP / 128) * (1024 / 128), 256, 0, stream>>>(
        Xhr + (size_t)gp0 * 128, W1hrT, (void*)Yhr, nullptr, CP, 1024, 128);
    // fused expand + layer-2: A2 = relu(A1(Yhr,Ycell,rel) @ W2T^T + b2)
    gemm_l12<<<(R >> 7) * (512 >> 8), 512, 0, stream>>>(
        Yhr, Ycell, b1, w1 + 384 * 1024, cellidx, relb, W2T, A2, b2,
        R, 512, 1024, gp0);
    tail34<<<R / 64, 256, 0, stream>>>(
        A2, W3T, W4T, b3, b4, w5, b5, out, R, gp0);
  }
}

// Round 4
// 1330.765 us; speedup vs baseline: 1.2887x; 1.2887x over previous
//
#include <hip/hip_runtime.h>

// JIIF fused pipeline v13 = v12 fusion with FIXED geometry.
//   v12 failure (R3): BM=128xBN=256 halved per-tile MFMA vs v11's 256^2 while
//   keeping per-tile overhead -> wall/K-tile unchanged (5200cyc), MfmaUtil 18%.
//   Construction also duplicated x2 (ntn=2) and sat on the critical path.
// v13 gemm_l12: BM=128 x BN=512 (FULL N, ntn=1), BK=64, 512 thr / 8 waves
//   (2M x 4N, per-wave 64x128 -> 64 MFMA/wave/tile = v11's amortization).
//   LDS 160KB (= CU max; AITER attn ships 160KB kernels): A 2x[128][64] 32KB
//   + B 2x[512][64] 128KB, both 8-wide XOR chunk-swizzled.
//   A-tile constructed in-kernel (A1 never in HBM; nc=4):
//     A1[4p+k][c] = relu(Yhrb[p][c] + mask*Ycell[cell[p][k]][c]
//                        + ry*w1rel0[c] + rx*w1rel1[c])
//   where Yhrb = Yhr + b1 (b1 folded in Yhr-GEMM epilogue, MODE 1) and w1rel
//   pre-converted to bf16 (prep_all) -> 6 loads/thread/tile (was 10), ~24
//   VGPR saved; est ~110 VGPR + 128 acc AGPR = 238 <= 256 (no spill).
//   Schedule (ONE barrier/tile, issue-early drain-late):
//     P0: ds_read frags ks0; issue A-gathers(t+1) + 8 B-stages(t+1);
//         sched_barrier(0) pin; 32 MFMA ks0.
//     P1: ds_read frags ks1; A_CONS (compiler vmcnt(8) waits gathers only);
//         vmcnt(0) [stages issued ~1200cyc ago -> no stall]; lgkmcnt(0);
//         s_barrier; 32 MFMA ks1.
// NOTES:
//  - R1(v10): 2-barrier 8-phase = null -> barrier count was the blocker.
//  - R2(v11): 1-barrier quadrant 256^2 -> 52.7 -> <39.6us (930 TF).
//  - R3(v12): BM=128xBN=256 fusion = 435 TF FAIL (amortization halved).
//  - R4/R5 (prev session): 512-thread fused tail spilled; tail34 stays 256t.

typedef unsigned short u16;
typedef unsigned int   u32;
typedef __bf16  bf16x8 __attribute__((ext_vector_type(8)));
typedef float   f32x4  __attribute__((ext_vector_type(4)));
typedef unsigned short u16x8 __attribute__((ext_vector_type(8)));

__device__ __forceinline__ u16 f2bf(float f) {
  u32 u = __float_as_uint(f);
  u32 r = (u + 0x7FFFu + ((u >> 16) & 1u)) >> 16;   // RNE
  return (u16)r;
}
__device__ __forceinline__ float bf2f(u16 v) {
  return __uint_as_float(((u32)v) << 16);
}
__device__ __forceinline__ void gload_lds16(const void* g, void* l) {
  __builtin_amdgcn_global_load_lds(
      (const __attribute__((address_space(1))) void*)g,
      (__attribute__((address_space(3))) void*)l, 16, 0, 0);
}

// ---------------------------------------------------------------------------
// gather_hr: per-pixel Xhr row (q_guide_hr, bf16[128]) + cellidx[pix][4] + rel[pix][4][2]
// ---------------------------------------------------------------------------
__global__ __launch_bounds__(256)
void gather_hr(const float* __restrict__ coord, const float* __restrict__ hr,
               u16* __restrict__ Xhr, int* __restrict__ cellidx, float* __restrict__ rel)
{
  __shared__ u16 hrT[64 * 130];
  __shared__ int nhrS[64];

  const int tid = threadIdx.x;
  const int pb  = blockIdx.x << 6;        // global pixel base
  const int b   = pb >> 16;
  const int n0  = pb & 65535;
  const float rh = 0.015625f;             // 1/64

  if (tid < 64) {
    const int n = n0 + tid;
    const float cy = coord[(size_t)(b * 65536 + n) * 2 + 0];
    const float cx = coord[(size_t)(b * 65536 + n) * 2 + 1];
    float fyh = (cy + 1.0f) * 128.0f - 0.5f;
    float fxh = (cx + 1.0f) * 128.0f - 0.5f;
    int iyh = (int)floorf(fyh + 0.5f);
    int ixh = (int)floorf(fxh + 0.5f);
    bool vh = (iyh >= 0 && iyh < 256 && ixh >= 0 && ixh < 256);
    nhrS[tid] = vh ? ((iyh << 8) + ixh) : -1;
#pragma unroll
    for (int k = 0; k < 4; ++k) {
      const float vx = (k < 2) ? -1.0f : 1.0f;
      const float vy = (k & 1) ? 1.0f : -1.0f;
      const float cyk = cy + vx * rh;
      const float cxk = cx + vy * rh;
      float fy = (cyk + 1.0f) * 32.0f - 0.5f;
      float fx = (cxk + 1.0f) * 32.0f - 0.5f;
      int iy = (int)floorf(fy + 0.5f);
      int ix = (int)floorf(fx + 0.5f);
      bool valid = (iy >= 0 && iy < 64 && ix >= 0 && ix < 64);
      int iyc = min(max(iy, 0), 63);
      int ixc = min(max(ix, 0), 63);
      float qy = valid ? ((-1.0f + rh) + (2.0f * rh) * (float)iyc) : 0.0f;
      float qx = valid ? ((-1.0f + rh) + (2.0f * rh) * (float)ixc) : 0.0f;
      const int p4 = ((pb + tid) << 2) + k;
      rel[2 * p4 + 0] = (cy - qy) * 64.0f;
      rel[2 * p4 + 1] = (cx - qx) * 64.0f;
      cellidx[p4] = valid ? (b * 4096 + iyc * 64 + ixc) : -1;
    }
  }
  __syncthreads();

  const size_t hb = (size_t)b * 128 * 65536;
  for (int e = tid; e < 64 * 128; e += 256) {
    const int pix = e & 63, c = e >> 6;
    const int n = nhrS[pix];
    const float v = (n >= 0) ? hr[hb + (size_t)c * 65536 + n] : 0.0f;
    hrT[pix * 130 + c] = f2bf(v);
  }
  __syncthreads();

  for (int e = tid; e < 64 * 128; e += 256) {
    const int pix = e >> 7, c = e & 127;
    Xhr[(size_t)(pb + pix) * 128 + c] = hrT[pix * 130 + c];
  }
}

// ---------------------------------------------------------------------------
// prep_cells: Xcell[cell][0:128]=feat, [128:256]=-lr  (bf16)
// ---------------------------------------------------------------------------
__global__ __launch_bounds__(256)
void prep_cells(const float* __restrict__ feat, const float* __restrict__ lr,
                u16* __restrict__ Xcell)
{
  __shared__ u16 t[64 * 258];
  const int tid = threadIdx.x;
  const int cb = blockIdx.x << 6;
  const int b = cb >> 12;
  const int local = cb & 4095;
  const size_t fb = (size_t)b * 128 * 4096;
  for (int e = tid; e < 64 * 128; e += 256) {
    const int cell = e & 63, c = e >> 6;
    const size_t idx = fb + (size_t)c * 4096 + local + cell;
    t[cell * 258 + c]       = f2bf(feat[idx]);
    t[cell * 258 + 128 + c] = (u16)(f2bf(lr[idx]) ^ 0x8000u);
  }
  __syncthreads();
  for (int e = tid; e < 64 * 256; e += 256) {
    const int cell = e >> 8, c = e & 255;
    Xcell[(size_t)(cb + cell) * 256 + c] = t[cell * 258 + c];
  }
}

// ---------------------------------------------------------------------------
// bf16 MFMA GEMM; BK=64 via two 32-k LDS slabs; 128x128 tile.
// MODE 0: C = relu(A@B^T + bias);  MODE 1: C = A@B^T + bias (no relu);
// MODE 3: C = A@B^T (raw). All bf16 out.
// ---------------------------------------------------------------------------
template<int MODE>
__global__ __launch_bounds__(256)
void gemm_bt(const u16* __restrict__ A, const u16* __restrict__ BT,
             void* __restrict__ Cout, const float* __restrict__ bias,
             int M, int N, int K)
{
  __shared__ __align__(16) u16 sh[16384];
  u16* As = sh;
  u16* Bs = sh + 8192;

  const int tid = threadIdx.x;
  const int w = tid >> 6;
  const int lane = tid & 63;
  const int ntn = N >> 7;
  const int nmt = M >> 7;
  int bm, bn;
  if ((nmt & 7) == 0) {
    const int xcd = blockIdx.x & 7;
    const int t = blockIdx.x >> 3;
    bn = t % ntn;
    bm = xcd * (nmt >> 3) + t / ntn;
  } else {
    bm = blockIdx.x / ntn;
    bn = blockIdx.x - bm * ntn;
  }
  const int m0 = bm << 7, n0 = bn << 7;

  const int lrow = tid >> 2;
  const int cc   = tid & 3;
  const int gcol = (cc ^ ((lrow >> 1) & 3)) << 3;

  f32x4 acc[4][4];
#pragma unroll
  for (int ii = 0; ii < 4; ++ii)
#pragma unroll
    for (int jj = 0; jj < 4; ++jj)
      acc[ii][jj] = f32x4{0.f, 0.f, 0.f, 0.f};

  const int mbase = (w & 1) << 6;
  const int nbase = (w >> 1) << 6;
  const int fr = lane & 15;
  const int fq = lane >> 4;
  const int rchunk = (fq ^ ((fr >> 1) & 3)) << 3;

  for (int kt = 0; kt < K; kt += 64) {
#pragma unroll
    for (int s = 0; s < 2; ++s) {
      const int kb = kt + (s << 5);
#pragma unroll
      for (int q = 0; q < 2; ++q) {
        const int mrow = (q << 6) + lrow;
        gload_lds16(A + (size_t)(m0 + mrow) * K + (kb + gcol),
                    (char*)As + (s << 13) + (q << 12) + (w << 10));
        gload_lds16(BT + (size_t)(n0 + mrow) * K + (kb + gcol),
                    (char*)Bs + (s << 13) + (q << 12) + (w << 10));
      }
    }
    __syncthreads();
#pragma unroll
    for (int s = 0; s < 2; ++s) {
      const int so = s << 12;
      bf16x8 af[4], bfv[4];
#pragma unroll
      for (int ii = 0; ii < 4; ++ii) {
        af[ii]  = *(const bf16x8*)(As + so + ((mbase + (ii << 4) + fr) << 5) + rchunk);
        bfv[ii] = *(const bf16x8*)(Bs + so + ((nbase + (ii << 4) + fr) << 5) + rchunk);
      }
#pragma unroll
      for (int ii = 0; ii < 4; ++ii)
#pragma unroll
        for (int jj = 0; jj < 4; ++jj)
          acc[ii][jj] = __builtin_amdgcn_mfma_f32_16x16x32_bf16(af[ii], bfv[jj], acc[ii][jj], 0, 0, 0);
    }
    __syncthreads();
  }

#pragma unroll
  for (int jj = 0; jj < 4; ++jj) {
    const int ncol = n0 + nbase + (jj << 4) + fr;
    const float bi = (MODE == 0 || MODE == 1) ? bias[ncol] : 0.f;
#pragma unroll
    for (int ii = 0; ii < 4; ++ii) {
#pragma unroll
      for (int r = 0; r < 4; ++r) {
        const int mrow = m0 + mbase + (ii << 4) + (fq << 2) + r;
        if (MODE == 0) {
          ((u16*)Cout)[(size_t)mrow * N + ncol] = f2bf(fmaxf(acc[ii][jj][r] + bi, 0.f));
        } else if (MODE == 1) {
          ((u16*)Cout)[(size_t)mrow * N + ncol] = f2bf(acc[ii][jj][r] + bi);
        } else {
          ((u16*)Cout)[(size_t)mrow * N + ncol] = f2bf(acc[ii][jj][r]);
        }
      }
    }
  }
}

// ---------------------------------------------------------------------------
// gemm_l12: fused expand(layer-1 combine) + layer-2 GEMM.  N=512 fixed.
//   C = relu(A1 @ W2T^T + b2), A1 row rr (pixel p=rr>>2, branch k=rr&3):
//     A1[rr][c] = relu(Yhrb[p][c] + mask*Ycell[cell[p][k]][c]
//                      + ry*w1rel0[c] + rx*w1rel1[c])      (Yhrb = Yhr + b1)
//   BM=128, BN=512, BK=64, 512 threads / 8 waves; per-wave C 64x128.
//   LDS 160KB: A 2x[128][64] u16 @0; B 2x[512][64] u16 @byte 32768.
// ---------------------------------------------------------------------------
__global__ __launch_bounds__(512, 2)
void gemm_l12(const u16* __restrict__ Yhr, const u16* __restrict__ Ycell,
              const u16* __restrict__ W1rb, const int* __restrict__ cellidx,
              const float* __restrict__ rel, const u16* __restrict__ BT,
              u16* __restrict__ Cout, const float* __restrict__ bias,
              int M, int K, int gp0)
{
  __shared__ __align__(16) u16 sh[81920];   // 160 KB
  char* shb = (char*)sh;
  const int N = 512;

  const int tid  = threadIdx.x;
  const int w    = tid >> 6;
  const int lane = tid & 63;
  const int wm = w >> 2, wn = w & 3;
  const int nwg = M >> 7;
  int bid = blockIdx.x;
  if ((nwg & 7) == 0) {
    const int cpx = nwg >> 3;
    bid = (bid & 7) * cpx + (bid >> 3);     // bijective XCD swizzle
  }
  const int m0 = bid << 7;
  const int NT = K >> 6;

  // staging/construction thread mapping
  const int srow = tid >> 3;                // 0..63
  const int cg   = tid & 7;
  const int gk   = (cg ^ (srow & 7)) << 3;  // swizzled source k offset (u16)
  const int swz8 = gk;                      // swizzled LDS chunk (u16)

  // fragment mapping
  const int fr = lane & 15;
  const int fq = lane >> 4;
  const int pk0 = ((fq)     ^ (fr & 7)) << 3;
  const int pk1 = ((4 + fq) ^ (fr & 7)) << 3;
  const int awr = (wm << 6) + fr;           // A frag row base (BM=128)
  const int bwr = (wn << 7) + fr;           // B frag row base (BN=512)

  // per-row persistent gather state (2 rows/thread: rr = srow, 64+srow)
  const int m04 = m0 >> 2;
  const int kk  = srow & 3;
  const int pA  = m04 + (srow >> 2);
  const int pB  = pA + 16;
  const int idxA = (gp0 + pA) * 4 + kk;
  const int idxB = (gp0 + pB) * 4 + kk;
  const int cellA = cellidx[idxA];
  const int cellB = cellidx[idxB];
  const float2 rvA = *(const float2*)(rel + (size_t)idxA * 2);
  const float2 rvB = *(const float2*)(rel + (size_t)idxB * 2);
  const float ryA = rvA.x, rxA = rvA.y, ryB = rvB.x, rxB = rvB.y;
  const u16 mkA = (u16)(cellA >= 0 ? 0xFFFFu : 0u);
  const u16 mkB = (u16)(cellB >= 0 ? 0xFFFFu : 0u);
  const u16x8 mskA = {mkA, mkA, mkA, mkA, mkA, mkA, mkA, mkA};
  const u16x8 mskB = {mkB, mkB, mkB, mkB, mkB, mkB, mkB, mkB};
  const u16* yA = Yhr + (size_t)pA * 1024;
  const u16* yB = Yhr + (size_t)pB * 1024;
  const u16* zA = Ycell + (size_t)max(cellA, 0) * 1024;
  const u16* zB = Ycell + (size_t)max(cellB, 0) * 1024;

  u16x8 yhA, yhB, ycA, ycB, cw0, cw1;

#define A_LOADS(kt1_) do { const int co_ = (kt1_) + (cg << 3); \
    yhA = *(const u16x8*)(yA + co_); yhB = *(const u16x8*)(yB + co_); \
    ycA = *(const u16x8*)(zA + co_); ycB = *(const u16x8*)(zB + co_); \
    cw0 = *(const u16x8*)(W1rb + co_); cw1 = *(const u16x8*)(W1rb + 1024 + co_); } while (0)

#define A_CONS(ab_) do { \
    const u16x8 za_ = ycA & mskA, zb_ = ycB & mskB; \
    u16x8 oA_, oB_; \
    _Pragma("unroll") \
    for (int j_ = 0; j_ < 8; ++j_) { \
      const float f0_ = bf2f(cw0[j_]), f1_ = bf2f(cw1[j_]); \
      float vA_ = bf2f(yhA[j_]) + bf2f(za_[j_]) + ryA * f0_ + rxA * f1_; \
      float vB_ = bf2f(yhB[j_]) + bf2f(zb_[j_]) + ryB * f0_ + rxB * f1_; \
      oA_[j_] = f2bf(fmaxf(vA_, 0.f)); \
      oB_[j_] = f2bf(fmaxf(vB_, 0.f)); \
    } \
    *(u16x8*)(sh + (ab_) + (srow << 6) + swz8) = oA_; \
    *(u16x8*)(sh + (ab_) + ((64 + srow) << 6) + swz8) = oB_; } while (0)

// 8 sub-stages cover B rows h*64+srow; dest byte 32768 + q*65536 + h*8192 + w*1024
#define STAGE_B(q_, kt_) do { \
    _Pragma("unroll") \
    for (int h_ = 0; h_ < 8; ++h_) \
      gload_lds16(BT + (size_t)((h_ << 6) + srow) * K + (kt_) + gk, \
                  shb + 32768 + ((q_) << 16) + (h_ << 13) + (w << 10)); } while (0)
#define BAR12()   asm volatile("s_barrier" ::: "memory")
#define VMC0()    asm volatile("s_waitcnt vmcnt(0)" ::: "memory")
#define LGKM0_()  asm volatile("s_waitcnt lgkmcnt(0)" ::: "memory")

  f32x4 acc[4][8];
#pragma unroll
  for (int i = 0; i < 4; ++i)
#pragma unroll
    for (int j = 0; j < 8; ++j)
      acc[i][j] = f32x4{0.f, 0.f, 0.f, 0.f};

  // ---- prologue: construct A(0) -> buf0; stage B(0) -> buf0 ----
  A_LOADS(0);
  A_CONS(0);              // compiler inserts vmcnt for the gather regs
  STAGE_B(0, 0);
  VMC0();
  LGKM0_();
  BAR12();

  for (int t = 0; t < NT; ++t) {
    const int Ab = (t & 1) << 13;           // u16 offset of A buf
    const int Bb = 16384 + ((t & 1) << 15); // u16 offset of B buf
    const int p1 = (t + 1) & 1;
    const int kt1 = (t + 1) << 6;
    const bool more = (t + 1 < NT);

    // ---- P0: k-slice 0 ----
    bf16x8 a0[4], g0[8];
#pragma unroll
    for (int i = 0; i < 4; ++i)
      a0[i] = *(const bf16x8*)(sh + Ab + ((awr + (i << 4)) << 6) + pk0);
#pragma unroll
    for (int j = 0; j < 8; ++j)
      g0[j] = *(const bf16x8*)(sh + Bb + ((bwr + (j << 4)) << 6) + pk0);
    if (more) {
      A_LOADS(kt1);                          // 6 gather loads (oldest)
      STAGE_B(p1, kt1);                      // 8 DMA stages (newest)
    }
    __builtin_amdgcn_sched_barrier(0);       // pin: loads issued before MFMA
    __builtin_amdgcn_s_setprio(1);
#pragma unroll
    for (int i = 0; i < 4; ++i)
#pragma unroll
      for (int j = 0; j < 8; ++j)
        acc[i][j] = __builtin_amdgcn_mfma_f32_16x16x32_bf16(a0[i], g0[j], acc[i][j], 0, 0, 0);
    __builtin_amdgcn_s_setprio(0);

    // ---- P1: k-slice 1 ----
    bf16x8 a1[4], g1[8];
#pragma unroll
    for (int i = 0; i < 4; ++i)
      a1[i] = *(const bf16x8*)(sh + Ab + ((awr + (i << 4)) << 6) + pk1);
#pragma unroll
    for (int j = 0; j < 8; ++j)
      g1[j] = *(const bf16x8*)(sh + Bb + ((bwr + (j << 4)) << 6) + pk1);
    if (more) A_CONS(p1 << 13);              // waits gathers (vmcnt(8)), not stages
    VMC0();                                  // stages issued ~1 phase ago
    LGKM0_();
    BAR12();
    __builtin_amdgcn_s_setprio(1);
#pragma unroll
    for (int i = 0; i < 4; ++i)
#pragma unroll
      for (int j = 0; j < 8; ++j)
        acc[i][j] = __builtin_amdgcn_mfma_f32_16x16x32_bf16(a1[i], g1[j], acc[i][j], 0, 0, 0);
    __builtin_amdgcn_s_setprio(0);
  }

#undef A_LOADS
#undef A_CONS
#undef STAGE_B
#undef BAR12
#undef VMC0
#undef LGKM0_

  // ---- epilogue: relu(acc + bias) -> bf16 ----
#pragma unroll
  for (int j = 0; j < 8; ++j) {
    const int ncol = (wn << 7) + (j << 4) + fr;
    const float bi = bias[ncol];
#pragma unroll
    for (int i = 0; i < 4; ++i) {
#pragma unroll
      for (int r = 0; r < 4; ++r) {
        const int mrow = m0 + (wm << 6) + (i << 4) + (fq << 2) + r;
        Cout[(size_t)mrow * N + ncol] = f2bf(fmaxf(acc[i][j][r] + bi, 0.f));
      }
    }
  }
}

// ---------------------------------------------------------------------------
// tail34: layers 3+4+5 for a 64-row block (16 pixels), 256 threads / 4 waves.
// ---------------------------------------------------------------------------
__global__ __launch_bounds__(256)
void tail34(const u16* __restrict__ A2, const u16* __restrict__ W3T,
            const u16* __restrict__ W4T, const float* __restrict__ b3,
            const float* __restrict__ b4, const float* __restrict__ w5,
            const float* __restrict__ b5, float* __restrict__ outp,
            int M, int gp0)
{
  __shared__ __align__(16) u16 sh[24576];   // 48 KB
  u16* As  = sh;            // L3 A staging: 2 slabs x (64x32)   [0,4096) u16
  u16* Bs  = sh + 4096;     // L3 B staging: 2 slabs x (256x32)  [4096,20480) u16
  u16* A3s = sh;            // A3 slabs: 8 x (64x32) [0,16384) u16 (aliases As/Bs)
  u16* W4s = sh + 16384;    // W4 staging: 2 slabs x (128x32) [16384,24576) u16
  // blend tile 64x136 aliases sh[0,8704) after layer-4.

  const int tid = threadIdx.x;
  const int w = tid >> 6;
  const int lane = tid & 63;
  const int nmt = M >> 6;
  int bm;
  if ((nmt & 7) == 0) bm = (blockIdx.x & 7) * (nmt >> 3) + (blockIdx.x >> 3);
  else bm = blockIdx.x;
  const int m0 = bm << 6;

  const int lrow = tid >> 2;                 // 0..63
  const int cc   = tid & 3;
  const int gcol = (cc ^ ((lrow >> 1) & 3)) << 3;

  const int fr = lane & 15;
  const int fq = lane >> 4;
  const int rchunk = (fq ^ ((fr >> 1) & 3)) << 3;
  const int nb3 = w << 6;                    // layer-3 wave col base

  // ---------------- layer-3 (M-tile 64, N 256, K 512) ----------------
  f32x4 acc3[4][4];
#pragma unroll
  for (int ii = 0; ii < 4; ++ii)
#pragma unroll
    for (int jj = 0; jj < 4; ++jj)
      acc3[ii][jj] = f32x4{0.f, 0.f, 0.f, 0.f};

  for (int kt = 0; kt < 512; kt += 64) {
#pragma unroll
    for (int s = 0; s < 2; ++s) {
      const int kb = kt + (s << 5);
      gload_lds16(A2 + (size_t)(m0 + lrow) * 512 + (kb + gcol),
                  (char*)As + (s << 12) + (w << 10));
#pragma unroll
      for (int q = 0; q < 4; ++q) {
        gload_lds16(W3T + (size_t)((q << 6) + lrow) * 512 + (kb + gcol),
                    (char*)Bs + (s << 14) + (q << 12) + (w << 10));
      }
    }
    __syncthreads();
#pragma unroll
    for (int s = 0; s < 2; ++s) {
      bf16x8 af[4], bfv[4];
#pragma unroll
      for (int ii = 0; ii < 4; ++ii) {
        af[ii]  = *(const bf16x8*)(As + (s << 11) + (((ii << 4) + fr) << 5) + rchunk);
        bfv[ii] = *(const bf16x8*)(Bs + (s << 13) + ((nb3 + (ii << 4) + fr) << 5) + rchunk);
      }
#pragma unroll
      for (int ii = 0; ii < 4; ++ii)
#pragma unroll
        for (int jj = 0; jj < 4; ++jj)
          acc3[ii][jj] = __builtin_amdgcn_mfma_f32_16x16x32_bf16(af[ii], bfv[jj], acc3[ii][jj], 0, 0, 0);
    }
    __syncthreads();
  }

  // ---------------- funnel: A3 = relu(acc3+b3) -> swizzled LDS slabs -------
  float b3v[4];
#pragma unroll
  for (int jj = 0; jj < 4; ++jj) b3v[jj] = b3[nb3 + (jj << 4) + fr];
#pragma unroll
  for (int jj = 0; jj < 4; ++jj) {
    const int col = nb3 + (jj << 4) + fr;
    const int sl = col >> 5, c = col & 31;
#pragma unroll
    for (int ii = 0; ii < 4; ++ii) {
#pragma unroll
      for (int r = 0; r < 4; ++r) {
        const int row = (ii << 4) + (fq << 2) + r;
        A3s[(sl << 11) + (row << 5) + (((c >> 3) ^ ((row >> 1) & 3)) << 3) + (c & 7)] =
            f2bf(fmaxf(acc3[ii][jj][r] + b3v[jj], 0.f));
      }
    }
  }

  // ---------------- layer-4 (K=256 from A3 slabs; N=128) ----------------
  f32x4 acc4[4][2];
#pragma unroll
  for (int ii = 0; ii < 4; ++ii)
#pragma unroll
    for (int jj = 0; jj < 2; ++jj)
      acc4[ii][jj] = f32x4{0.f, 0.f, 0.f, 0.f};
  const int nb4 = w << 5;

  for (int kt4 = 0; kt4 < 4; ++kt4) {
#pragma unroll
    for (int s = 0; s < 2; ++s) {
      const int kb = (kt4 << 6) + (s << 5);
#pragma unroll
      for (int q = 0; q < 2; ++q) {
        gload_lds16(W4T + (size_t)((q << 6) + lrow) * 256 + (kb + gcol),
                    (char*)W4s + (s << 13) + (q << 12) + (w << 10));
      }
    }
    __syncthreads();   // W4 visible; first iter also publishes the A3 funnel
#pragma unroll
    for (int s = 0; s < 2; ++s) {
      const int sl = (kt4 << 1) + s;
      bf16x8 af[4], bfv[2];
#pragma unroll
      for (int ii = 0; ii < 4; ++ii)
        af[ii] = *(const bf16x8*)(A3s + (sl << 11) + (((ii << 4) + fr) << 5) + rchunk);
#pragma unroll
      for (int jj = 0; jj < 2; ++jj)
        bfv[jj] = *(const bf16x8*)(W4s + (s << 12) + ((nb4 + (jj << 4) + fr) << 5) + rchunk);
#pragma unroll
      for (int ii = 0; ii < 4; ++ii)
#pragma unroll
        for (int jj = 0; jj < 2; ++jj)
          acc4[ii][jj] = __builtin_amdgcn_mfma_f32_16x16x32_bf16(af[ii], bfv[jj], acc4[ii][jj], 0, 0, 0);
    }
    __syncthreads();
  }

  // ---------------- layer-5 + softmax blend ----------------
  float b4v[2];
#pragma unroll
  for (int jj = 0; jj < 2; ++jj) b4v[jj] = b4[nb4 + (jj << 4) + fr];
#pragma unroll
  for (int ii = 0; ii < 4; ++ii) {
#pragma unroll
    for (int jj = 0; jj < 2; ++jj) {
      const int col = nb4 + (jj << 4) + fr;
#pragma unroll
      for (int r = 0; r < 4; ++r) {
        const int row = (ii << 4) + (fq << 2) + r;
        sh[row * 136 + col] = f2bf(fmaxf(acc4[ii][jj][r] + b4v[jj], 0.f));
      }
    }
  }
  const int cbase = fr << 3;
  float w50[8], w51[8];
#pragma unroll
  for (int j = 0; j < 8; ++j) {
    w50[j] = w5[((cbase + j) << 1) + 0];
    w51[j] = w5[((cbase + j) << 1) + 1];
  }
  const float b50 = b5[0], b51 = b5[1];
  __syncthreads();

#pragma unroll
  for (int rep = 0; rep < 4; ++rep) {
    const int pl = (rep << 2) + w;            // block-local pixel 0..15
    const int row = (pl << 2) + fq;           // branch k = fq
    const u16x8 v = *(const u16x8*)(sh + row * 136 + cbase);
    float s0 = 0.f, s1 = 0.f;
#pragma unroll
    for (int j = 0; j < 8; ++j) {
      const float a = bf2f(v[j]);
      s0 += a * w50[j];
      s1 += a * w51[j];
    }
#pragma unroll
    for (int off = 8; off >= 1; off >>= 1) {
      s0 += __shfl_xor(s0, off, 16);
      s1 += __shfl_xor(s1, off, 16);
    }
    float p0[4], p1[4];
#pragma unroll
    for (int k = 0; k < 4; ++k) {
      p0[k] = __shfl(s0, k << 4, 64) + b50;
      p1[k] = __shfl(s1, k << 4, 64) + b51;
    }
    if (lane == 0) {
      float mx = fmaxf(fmaxf(p1[0], p1[1]), fmaxf(p1[2], p1[3]));
      float e0 = expf(p1[0] - mx), e1 = expf(p1[1] - mx);
      float e2 = expf(p1[2] - mx), e3 = expf(p1[3] - mx);
      outp[gp0 + (m0 >> 2) + pl] =
          (p0[0] * e0 + p0[1] * e1 + p0[2] * e2 + p0[3] * e3) / (e0 + e1 + e2 + e3);
    }
  }
}

// ---------------------------------------------------------------------------
// prep_all: all transposed bf16 weights in one dispatch (+ bf16 w1rel).
// ---------------------------------------------------------------------------
__global__ __launch_bounds__(256)
void prep_all(const float* __restrict__ w1, const float* __restrict__ w2,
              const float* __restrict__ w3, const float* __restrict__ w4,
              u16* __restrict__ W1hrT, u16* __restrict__ W1cellT,
              u16* __restrict__ W2T, u16* __restrict__ W3T, u16* __restrict__ W4T,
              u16* __restrict__ W1rb)
{
  const int idx = blockIdx.x * 256 + threadIdx.x;
  if (idx < 131072) {
    const int n = idx >> 7, k = idx & 127;
    W1hrT[idx] = f2bf(w1[(128 + k) * 1024 + n] + w1[(256 + k) * 1024 + n]);
  } else if (idx < 393216) {
    const int i = idx - 131072;
    const int n = i >> 8, k = i & 255;
    W1cellT[i] = f2bf((k < 128) ? w1[k * 1024 + n] : w1[(128 + k) * 1024 + n]);
  } else if (idx < 917504) {
    const int i = idx - 393216;
    const int n = i >> 10, k = i & 1023;
    W2T[i] = f2bf(w2[k * 512 + n]);
  } else if (idx < 1048576) {
    const int i = idx - 917504;
    const int n = i >> 9, k = i & 511;
    W3T[i] = f2bf(w3[k * 256 + n]);
  } else if (idx < 1081344) {
    const int i = idx - 1048576;
    const int n = i >> 8, k = i & 255;
    W4T[i] = f2bf(w4[k * 128 + n]);
  } else if (idx < 1083392) {
    const int i = idx - 1081344;
    W1rb[i] = f2bf(w1[384 * 1024 + i]);      // w1rel rows 384,385 -> bf16
  }
}

// ---------------------------------------------------------------------------
extern "C" void kernel_launch(void* const* d_in, const int* in_sizes, int n_in,
                              void* d_out, int out_size, void* d_ws, size_t ws_size,
                              hipStream_t stream)
{
  const float* feat  = (const float*)d_in[0];
  const float* coord = (const float*)d_in[1];
  const float* hrg   = (const float*)d_in[2];
  const float* lrg   = (const float*)d_in[3];
  const float* w1 = (const float*)d_in[4];
  const float* b1 = (const float*)d_in[5];
  const float* w2 = (const float*)d_in[6];
  const float* b2 = (const float*)d_in[7];
  const float* w3 = (const float*)d_in[8];
  const float* b3 = (const float*)d_in[9];
  const float* w4 = (const float*)d_in[10];
  const float* b4 = (const float*)d_in[11];
  const float* w5 = (const float*)d_in[12];
  const float* b5 = (const float*)d_in[13];
  float* out = (float*)d_out;

  char* base = (char*)d_ws;
  u16* W1hrT   = (u16*)base;                       // [1024][128]
  u16* W1cellT = W1hrT + 1024 * 128;               // [1024][256]
  u16* W2T     = W1cellT + 1024 * 256;             // [512][1024]
  u16* W3T     = W2T + 512 * 1024;                 // [256][512]
  u16* W4T     = W3T + 256 * 512;                  // [128][256]
  u16* W1rb    = W4T + 128 * 256;                  // [2][1024] bf16 w1rel
  u16* Xcell   = W1rb + 2048;                      // [8192][256]
  u16* Ycell   = Xcell + 8192 * 256;               // [8192][1024] bf16
  u16* Xhr     = Ycell + (size_t)8192 * 1024;      // [131072][128]
  float* relb  = (float*)(Xhr + (size_t)131072 * 128); // [131072][4][2]
  int* cellidx = (int*)(relb + (size_t)131072 * 8);    // [131072][4]
  char* chunk_base = (char*)(cellidx + (size_t)131072 * 4);
  const size_t fixed = (size_t)(chunk_base - base);

  const int NP = 131072;
  // per-pixel chunk bytes: Yhr 2048 + A2 4096 = 6144 (A1 fused away)
  int nc = 1;
  while (nc < 128 && fixed + (size_t)(NP / nc) * 6144ULL > ws_size) nc <<= 1;
  const int CP = NP / nc;
  const int R = CP * 4;

  u16* Yhr = (u16*)chunk_base;          // [CP][1024] bf16 (Yhr + b1 folded)
  u16* A2  = Yhr + (size_t)CP * 1024;   // [R][512] bf16

  prep_all<<<4232, 256, 0, stream>>>(w1, w2, w3, w4, W1hrT, W1cellT, W2T, W3T,
                                     W4T, W1rb);
  gather_hr<<<NP / 64, 256, 0, stream>>>(coord, hrg, Xhr, cellidx, relb);
  prep_cells<<<8192 / 64, 256, 0, stream>>>(feat, lrg, Xcell);
  // Ycell = Xcell @ W1cellT^T (raw bf16)
  gemm_bt<3><<<(8192 / 128) * (1024 / 128), 256, 0, stream>>>(
      Xcell, W1cellT, (void*)Ycell, nullptr, 8192, 1024, 256);

  for (int ch = 0; ch < nc; ++ch) {
    const int gp0 = ch * CP;
    // Yhrb = Xhr_chunk @ W1hrT^T + b1 (MODE 1: bias, no relu)
    gemm_bt<1><<<(CP / 128) * (1024 / 128), 256, 0, stream>>>(
        Xhr + (size_t)gp0 * 128, W1hrT, (void*)Yhr, b1, CP, 1024, 128);
    // fused expand + layer-2: A2 = relu(A1(Yhrb,Ycell,rel) @ W2T^T + b2)
    gemm_l12<<<(R >> 7), 512, 0, stream>>>(
        Yhr, Ycell, W1rb, cellidx, relb, W2T, A2, b2, R, 1024, gp0);
    tail34<<<R / 64, 256, 0, stream>>>(
        A2, W3T, W4T, b3, b4, w5, b5, out, R, gp0);
  }
}

// Round 6
// 1204.759 us; speedup vs baseline: 1.4234x; 1.1046x over previous
//
#include <hip/hip_runtime.h>

// JIIF fused pipeline v14 (RESUBMIT — R5 bench was an infra failure:
// "MI355X container failed twice", no compile/correctness signal. Schedule
// re-audited: barriers uniform, vmcnt ledger always satisfiable, LDS
// write-after-read hazards all barrier-separated. Unchanged from R4 design.)
//
// v14 = v13 with construction moved OFF the critical path.
//   R4 evidence: gemm_l12 657 TF = unfused rate; T_tile 7850 cyc vs v11's
//   5400 for identical MFMA work -> the +2450 is A-construction serialized
//   (A_CONS sat in P1 BEFORE the tile barrier -> never overlaps MFMA; its
//   gather-wait fired before any MFMA issued). Register wall (128 VGPR +
//   128 AGPR = 256 = 2 waves/SIMD exactly) forbids depth-2 reg prefetch.
// v14 schedule (zero extra regs, one barrier/tile):
//   P0: frag ks0; STAGE_B(t+1) [8 DMA]; setprio{32 MFMA ks0};
//       A_CONS(t+1) [uses gather set filled at t-1 P1; compiler vmcnt AFTER
//       MFMA issue; ~360cyc VALU + 2 ds_write issue under MFMA pipe shadow]
//   P1: frag ks1; A_GATH(t+2) [6 loads -> same set, WAR-safe: consumed t P0];
//       vmcnt(6) [stages older, gathers newer -> forces stages only];
//       lgkm(0) [drains CONS writes + all frag reads]; s_barrier;
//       setprio{32 MFMA ks1}.
//   Hazard ledger: CONS at t P0 writes Abuf((t+1)&1) -- last READ at t-1 P1,
//   drained by that wave's lgkm(0) before the t-1 barrier; write is post-
//   barrier. Stages write Bbuf((t+1)&1): same argument. Gathers cross the
//   barrier in flight (registers only, no LDS hazard).
// NOTES:
//  - R1(v10): 2-barrier 8-phase = null -> barrier count was the blocker.
//  - R2(v11): 1-barrier quadrant 256^2 -> 52.7 -> <39.6us (~930 TF).
//  - R3(v12): BM=128xBN=256 fusion = 435 TF FAIL (amortization halved).
//  - R4(v13): BM=128xBN=512 fusion = 657 TF; total 1331us. Construction
//    serialized; sched_barrier(0) pinned it out of the MFMA region (dropped).
//  - Register budget is EXACTLY at the 2-waves/SIMD cliff: do not add
//    persistent VGPRs to gemm_l12.

typedef unsigned short u16;
typedef unsigned int   u32;
typedef __bf16  bf16x8 __attribute__((ext_vector_type(8)));
typedef float   f32x4  __attribute__((ext_vector_type(4)));
typedef unsigned short u16x8 __attribute__((ext_vector_type(8)));

__device__ __forceinline__ u16 f2bf(float f) {
  u32 u = __float_as_uint(f);
  u32 r = (u + 0x7FFFu + ((u >> 16) & 1u)) >> 16;   // RNE
  return (u16)r;
}
__device__ __forceinline__ float bf2f(u16 v) {
  return __uint_as_float(((u32)v) << 16);
}
__device__ __forceinline__ void gload_lds16(const void* g, void* l) {
  __builtin_amdgcn_global_load_lds(
      (const __attribute__((address_space(1))) void*)g,
      (__attribute__((address_space(3))) void*)l, 16, 0, 0);
}

// ---------------------------------------------------------------------------
// gather_hr: per-pixel Xhr row (q_guide_hr, bf16[128]) + cellidx[pix][4] + rel[pix][4][2]
// ---------------------------------------------------------------------------
__global__ __launch_bounds__(256)
void gather_hr(const float* __restrict__ coord, const float* __restrict__ hr,
               u16* __restrict__ Xhr, int* __restrict__ cellidx, float* __restrict__ rel)
{
  __shared__ u16 hrT[64 * 130];
  __shared__ int nhrS[64];

  const int tid = threadIdx.x;
  const int pb  = blockIdx.x << 6;        // global pixel base
  const int b   = pb >> 16;
  const int n0  = pb & 65535;
  const float rh = 0.015625f;             // 1/64

  if (tid < 64) {
    const int n = n0 + tid;
    const float cy = coord[(size_t)(b * 65536 + n) * 2 + 0];
    const float cx = coord[(size_t)(b * 65536 + n) * 2 + 1];
    float fyh = (cy + 1.0f) * 128.0f - 0.5f;
    float fxh = (cx + 1.0f) * 128.0f - 0.5f;
    int iyh = (int)floorf(fyh + 0.5f);
    int ixh = (int)floorf(fxh + 0.5f);
    bool vh = (iyh >= 0 && iyh < 256 && ixh >= 0 && ixh < 256);
    nhrS[tid] = vh ? ((iyh << 8) + ixh) : -1;
#pragma unroll
    for (int k = 0; k < 4; ++k) {
      const float vx = (k < 2) ? -1.0f : 1.0f;
      const float vy = (k & 1) ? 1.0f : -1.0f;
      const float cyk = cy + vx * rh;
      const float cxk = cx + vy * rh;
      float fy = (cyk + 1.0f) * 32.0f - 0.5f;
      float fx = (cxk + 1.0f) * 32.0f - 0.5f;
      int iy = (int)floorf(fy + 0.5f);
      int ix = (int)floorf(fx + 0.5f);
      bool valid = (iy >= 0 && iy < 64 && ix >= 0 && ix < 64);
      int iyc = min(max(iy, 0), 63);
      int ixc = min(max(ix, 0), 63);
      float qy = valid ? ((-1.0f + rh) + (2.0f * rh) * (float)iyc) : 0.0f;
      float qx = valid ? ((-1.0f + rh) + (2.0f * rh) * (float)ixc) : 0.0f;
      const int p4 = ((pb + tid) << 2) + k;
      rel[2 * p4 + 0] = (cy - qy) * 64.0f;
      rel[2 * p4 + 1] = (cx - qx) * 64.0f;
      cellidx[p4] = valid ? (b * 4096 + iyc * 64 + ixc) : -1;
    }
  }
  __syncthreads();

  const size_t hb = (size_t)b * 128 * 65536;
  for (int e = tid; e < 64 * 128; e += 256) {
    const int pix = e & 63, c = e >> 6;
    const int n = nhrS[pix];
    const float v = (n >= 0) ? hr[hb + (size_t)c * 65536 + n] : 0.0f;
    hrT[pix * 130 + c] = f2bf(v);
  }
  __syncthreads();

  for (int e = tid; e < 64 * 128; e += 256) {
    const int pix = e >> 7, c = e & 127;
    Xhr[(size_t)(pb + pix) * 128 + c] = hrT[pix * 130 + c];
  }
}

// ---------------------------------------------------------------------------
// prep_cells: Xcell[cell][0:128]=feat, [128:256]=-lr  (bf16)
// ---------------------------------------------------------------------------
__global__ __launch_bounds__(256)
void prep_cells(const float* __restrict__ feat, const float* __restrict__ lr,
                u16* __restrict__ Xcell)
{
  __shared__ u16 t[64 * 258];
  const int tid = threadIdx.x;
  const int cb = blockIdx.x << 6;
  const int b = cb >> 12;
  const int local = cb & 4095;
  const size_t fb = (size_t)b * 128 * 4096;
  for (int e = tid; e < 64 * 128; e += 256) {
    const int cell = e & 63, c = e >> 6;
    const size_t idx = fb + (size_t)c * 4096 + local + cell;
    t[cell * 258 + c]       = f2bf(feat[idx]);
    t[cell * 258 + 128 + c] = (u16)(f2bf(lr[idx]) ^ 0x8000u);
  }
  __syncthreads();
  for (int e = tid; e < 64 * 256; e += 256) {
    const int cell = e >> 8, c = e & 255;
    Xcell[(size_t)(cb + cell) * 256 + c] = t[cell * 258 + c];
  }
}

// ---------------------------------------------------------------------------
// bf16 MFMA GEMM; BK=64 via two 32-k LDS slabs; 128x128 tile.
// MODE 0: C = relu(A@B^T + bias);  MODE 1: C = A@B^T + bias (no relu);
// MODE 3: C = A@B^T (raw). All bf16 out.
// ---------------------------------------------------------------------------
template<int MODE>
__global__ __launch_bounds__(256)
void gemm_bt(const u16* __restrict__ A, const u16* __restrict__ BT,
             void* __restrict__ Cout, const float* __restrict__ bias,
             int M, int N, int K)
{
  __shared__ __align__(16) u16 sh[16384];
  u16* As = sh;
  u16* Bs = sh + 8192;

  const int tid = threadIdx.x;
  const int w = tid >> 6;
  const int lane = tid & 63;
  const int ntn = N >> 7;
  const int nmt = M >> 7;
  int bm, bn;
  if ((nmt & 7) == 0) {
    const int xcd = blockIdx.x & 7;
    const int t = blockIdx.x >> 3;
    bn = t % ntn;
    bm = xcd * (nmt >> 3) + t / ntn;
  } else {
    bm = blockIdx.x / ntn;
    bn = blockIdx.x - bm * ntn;
  }
  const int m0 = bm << 7, n0 = bn << 7;

  const int lrow = tid >> 2;
  const int cc   = tid & 3;
  const int gcol = (cc ^ ((lrow >> 1) & 3)) << 3;

  f32x4 acc[4][4];
#pragma unroll
  for (int ii = 0; ii < 4; ++ii)
#pragma unroll
    for (int jj = 0; jj < 4; ++jj)
      acc[ii][jj] = f32x4{0.f, 0.f, 0.f, 0.f};

  const int mbase = (w & 1) << 6;
  const int nbase = (w >> 1) << 6;
  const int fr = lane & 15;
  const int fq = lane >> 4;
  const int rchunk = (fq ^ ((fr >> 1) & 3)) << 3;

  for (int kt = 0; kt < K; kt += 64) {
#pragma unroll
    for (int s = 0; s < 2; ++s) {
      const int kb = kt + (s << 5);
#pragma unroll
      for (int q = 0; q < 2; ++q) {
        const int mrow = (q << 6) + lrow;
        gload_lds16(A + (size_t)(m0 + mrow) * K + (kb + gcol),
                    (char*)As + (s << 13) + (q << 12) + (w << 10));
        gload_lds16(BT + (size_t)(n0 + mrow) * K + (kb + gcol),
                    (char*)Bs + (s << 13) + (q << 12) + (w << 10));
      }
    }
    __syncthreads();
#pragma unroll
    for (int s = 0; s < 2; ++s) {
      const int so = s << 12;
      bf16x8 af[4], bfv[4];
#pragma unroll
      for (int ii = 0; ii < 4; ++ii) {
        af[ii]  = *(const bf16x8*)(As + so + ((mbase + (ii << 4) + fr) << 5) + rchunk);
        bfv[ii] = *(const bf16x8*)(Bs + so + ((nbase + (ii << 4) + fr) << 5) + rchunk);
      }
#pragma unroll
      for (int ii = 0; ii < 4; ++ii)
#pragma unroll
        for (int jj = 0; jj < 4; ++jj)
          acc[ii][jj] = __builtin_amdgcn_mfma_f32_16x16x32_bf16(af[ii], bfv[jj], acc[ii][jj], 0, 0, 0);
    }
    __syncthreads();
  }

#pragma unroll
  for (int jj = 0; jj < 4; ++jj) {
    const int ncol = n0 + nbase + (jj << 4) + fr;
    const float bi = (MODE == 0 || MODE == 1) ? bias[ncol] : 0.f;
#pragma unroll
    for (int ii = 0; ii < 4; ++ii) {
#pragma unroll
      for (int r = 0; r < 4; ++r) {
        const int mrow = m0 + mbase + (ii << 4) + (fq << 2) + r;
        if (MODE == 0) {
          ((u16*)Cout)[(size_t)mrow * N + ncol] = f2bf(fmaxf(acc[ii][jj][r] + bi, 0.f));
        } else if (MODE == 1) {
          ((u16*)Cout)[(size_t)mrow * N + ncol] = f2bf(acc[ii][jj][r] + bi);
        } else {
          ((u16*)Cout)[(size_t)mrow * N + ncol] = f2bf(acc[ii][jj][r]);
        }
      }
    }
  }
}

// ---------------------------------------------------------------------------
// gemm_l12: fused expand(layer-1 combine) + layer-2 GEMM.  N=512 fixed.
//   C = relu(A1 @ W2T^T + b2), A1 row rr (pixel p=rr>>2, branch k=rr&3):
//     A1[rr][c] = relu(Yhrb[p][c] + mask*Ycell[cell[p][k]][c]
//                      + ry*w1rel0[c] + rx*w1rel1[c])      (Yhrb = Yhr + b1)
//   BM=128, BN=512, BK=64, 512 threads / 8 waves; per-wave C 64x128.
//   LDS 160KB: A 2x[128][64] u16 @0; B 2x[512][64] u16 @byte 32768.
//   Schedule: see file header (v14).
// ---------------------------------------------------------------------------
__global__ __launch_bounds__(512, 2)
void gemm_l12(const u16* __restrict__ Yhr, const u16* __restrict__ Ycell,
              const u16* __restrict__ W1rb, const int* __restrict__ cellidx,
              const float* __restrict__ rel, const u16* __restrict__ BT,
              u16* __restrict__ Cout, const float* __restrict__ bias,
              int M, int K, int gp0)
{
  __shared__ __align__(16) u16 sh[81920];   // 160 KB
  char* shb = (char*)sh;
  const int N = 512;

  const int tid  = threadIdx.x;
  const int w    = tid >> 6;
  const int lane = tid & 63;
  const int wm = w >> 2, wn = w & 3;
  const int nwg = M >> 7;
  int bid = blockIdx.x;
  if ((nwg & 7) == 0) {
    const int cpx = nwg >> 3;
    bid = (bid & 7) * cpx + (bid >> 3);     // bijective XCD swizzle
  }
  const int m0 = bid << 7;
  const int NT = K >> 6;

  // staging/construction thread mapping
  const int srow = tid >> 3;                // 0..63
  const int cg   = tid & 7;
  const int gk   = (cg ^ (srow & 7)) << 3;  // swizzled source k offset (u16)
  const int swz8 = gk;                      // swizzled LDS chunk (u16)

  // fragment mapping
  const int fr = lane & 15;
  const int fq = lane >> 4;
  const int pk0 = ((fq)     ^ (fr & 7)) << 3;
  const int pk1 = ((4 + fq) ^ (fr & 7)) << 3;
  const int awr = (wm << 6) + fr;           // A frag row base (BM=128)
  const int bwr = (wn << 7) + fr;           // B frag row base (BN=512)

  // per-row persistent gather state (2 rows/thread: rr = srow, 64+srow)
  const int m04 = m0 >> 2;
  const int kk  = srow & 3;
  const int pA  = m04 + (srow >> 2);
  const int pB  = pA + 16;
  const int idxA = (gp0 + pA) * 4 + kk;
  const int idxB = (gp0 + pB) * 4 + kk;
  const int cellA = cellidx[idxA];
  const int cellB = cellidx[idxB];
  const float2 rvA = *(const float2*)(rel + (size_t)idxA * 2);
  const float2 rvB = *(const float2*)(rel + (size_t)idxB * 2);
  const float ryA = rvA.x, rxA = rvA.y, ryB = rvB.x, rxB = rvB.y;
  const u16 mkA = (u16)(cellA >= 0 ? 0xFFFFu : 0u);
  const u16 mkB = (u16)(cellB >= 0 ? 0xFFFFu : 0u);
  const u16x8 mskA = {mkA, mkA, mkA, mkA, mkA, mkA, mkA, mkA};
  const u16x8 mskB = {mkB, mkB, mkB, mkB, mkB, mkB, mkB, mkB};
  const u16* yA = Yhr + (size_t)pA * 1024;
  const u16* yB = Yhr + (size_t)pB * 1024;
  const u16* zA = Ycell + (size_t)max(cellA, 0) * 1024;
  const u16* zB = Ycell + (size_t)max(cellB, 0) * 1024;

  u16x8 yhA, yhB, ycA, ycB, cw0, cw1;

#define A_LOADS(kt1_) do { const int co_ = (kt1_) + (cg << 3); \
    yhA = *(const u16x8*)(yA + co_); yhB = *(const u16x8*)(yB + co_); \
    ycA = *(const u16x8*)(zA + co_); ycB = *(const u16x8*)(zB + co_); \
    cw0 = *(const u16x8*)(W1rb + co_); cw1 = *(const u16x8*)(W1rb + 1024 + co_); } while (0)

#define A_CONS(ab_) do { \
    const u16x8 za_ = ycA & mskA, zb_ = ycB & mskB; \
    u16x8 oA_, oB_; \
    _Pragma("unroll") \
    for (int j_ = 0; j_ < 8; ++j_) { \
      const float f0_ = bf2f(cw0[j_]), f1_ = bf2f(cw1[j_]); \
      float vA_ = bf2f(yhA[j_]) + bf2f(za_[j_]) + ryA * f0_ + rxA * f1_; \
      float vB_ = bf2f(yhB[j_]) + bf2f(zb_[j_]) + ryB * f0_ + rxB * f1_; \
      oA_[j_] = f2bf(fmaxf(vA_, 0.f)); \
      oB_[j_] = f2bf(fmaxf(vB_, 0.f)); \
    } \
    *(u16x8*)(sh + (ab_) + (srow << 6) + swz8) = oA_; \
    *(u16x8*)(sh + (ab_) + ((64 + srow) << 6) + swz8) = oB_; } while (0)

// 8 sub-stages cover B rows h*64+srow; dest byte 32768 + q*65536 + h*8192 + w*1024
#define STAGE_B(q_, kt_) do { \
    _Pragma("unroll") \
    for (int h_ = 0; h_ < 8; ++h_) \
      gload_lds16(BT + (size_t)((h_ << 6) + srow) * K + (kt_) + gk, \
                  shb + 32768 + ((q_) << 16) + (h_ << 13) + (w << 10)); } while (0)
#define BAR12()   asm volatile("s_barrier" ::: "memory")
#define VMC(n)    asm volatile("s_waitcnt vmcnt(" #n ")" ::: "memory")
#define LGKM0_()  asm volatile("s_waitcnt lgkmcnt(0)" ::: "memory")

  f32x4 acc[4][8];
#pragma unroll
  for (int i = 0; i < 4; ++i)
#pragma unroll
    for (int j = 0; j < 8; ++j)
      acc[i][j] = f32x4{0.f, 0.f, 0.f, 0.f};

  // ---- prologue: build A(0)->buf0, stage B(0)->buf0, prefetch A(1) regs ----
  A_LOADS(0);
  A_CONS(0);                 // compiler waits the 6 gathers
  STAGE_B(0, 0);             // 8 stages (older than next gathers)
  if (NT > 1) { A_LOADS(64); VMC(6); }   // force stages; A(1) stays in flight
  else VMC(0);
  LGKM0_();
  BAR12();

  for (int t = 0; t < NT; ++t) {
    const int Ab = (t & 1) << 13;           // u16 offset of A buf
    const int Bb = 16384 + ((t & 1) << 15); // u16 offset of B buf
    const int p1 = (t + 1) & 1;
    const int kt1 = (t + 1) << 6;
    const bool mA_ = (t + 1 < NT);
    const bool mG_ = (t + 2 < NT);

    // ---- P0: k-slice 0 ----
    bf16x8 a0[4], g0[8];
#pragma unroll
    for (int i = 0; i < 4; ++i)
      a0[i] = *(const bf16x8*)(sh + Ab + ((awr + (i << 4)) << 6) + pk0);
#pragma unroll
    for (int j = 0; j < 8; ++j)
      g0[j] = *(const bf16x8*)(sh + Bb + ((bwr + (j << 4)) << 6) + pk0);
    if (mA_) STAGE_B(p1, kt1);               // 8 DMA stages, issue early
    __builtin_amdgcn_s_setprio(1);
#pragma unroll
    for (int i = 0; i < 4; ++i)
#pragma unroll
      for (int j = 0; j < 8; ++j)
        acc[i][j] = __builtin_amdgcn_mfma_f32_16x16x32_bf16(a0[i], g0[j], acc[i][j], 0, 0, 0);
    __builtin_amdgcn_s_setprio(0);
    // construction issues under the MFMA pipe shadow (gather-wait after
    // MFMA issue; writes go to Abuf(p1), last read drained at t-1 barrier)
    if (mA_) A_CONS(p1 << 13);

    // ---- P1: k-slice 1 ----
    bf16x8 a1[4], g1[8];
#pragma unroll
    for (int i = 0; i < 4; ++i)
      a1[i] = *(const bf16x8*)(sh + Ab + ((awr + (i << 4)) << 6) + pk1);
#pragma unroll
    for (int j = 0; j < 8; ++j)
      g1[j] = *(const bf16x8*)(sh + Bb + ((bwr + (j << 4)) << 6) + pk1);
    if (mG_) A_LOADS((t + 2) << 6);          // refill gather set (WAR-safe)
    if (mG_) VMC(6); else VMC(0);            // force stages; gathers in flight
    LGKM0_();                                // CONS writes + frag reads done
    BAR12();
    __builtin_amdgcn_s_setprio(1);
#pragma unroll
    for (int i = 0; i < 4; ++i)
#pragma unroll
      for (int j = 0; j < 8; ++j)
        acc[i][j] = __builtin_amdgcn_mfma_f32_16x16x32_bf16(a1[i], g1[j], acc[i][j], 0, 0, 0);
    __builtin_amdgcn_s_setprio(0);
  }

#undef A_LOADS
#undef A_CONS
#undef STAGE_B
#undef BAR12
#undef VMC
#undef LGKM0_

  // ---- epilogue: relu(acc + bias) -> bf16 ----
#pragma unroll
  for (int j = 0; j < 8; ++j) {
    const int ncol = (wn << 7) + (j << 4) + fr;
    const float bi = bias[ncol];
#pragma unroll
    for (int i = 0; i < 4; ++i) {
#pragma unroll
      for (int r = 0; r < 4; ++r) {
        const int mrow = m0 + (wm << 6) + (i << 4) + (fq << 2) + r;
        Cout[(size_t)mrow * N + ncol] = f2bf(fmaxf(acc[i][j][r] + bi, 0.f));
      }
    }
  }
}

// ---------------------------------------------------------------------------
// tail34: layers 3+4+5 for a 64-row block (16 pixels), 256 threads / 4 waves.
// ---------------------------------------------------------------------------
__global__ __launch_bounds__(256)
void tail34(const u16* __restrict__ A2, const u16* __restrict__ W3T,
            const u16* __restrict__ W4T, const float* __restrict__ b3,
            const float* __restrict__ b4, const float* __restrict__ w5,
            const float* __restrict__ b5, float* __restrict__ outp,
            int M, int gp0)
{
  __shared__ __align__(16) u16 sh[24576];   // 48 KB
  u16* As  = sh;            // L3 A staging: 2 slabs x (64x32)   [0,4096) u16
  u16* Bs  = sh + 4096;     // L3 B staging: 2 slabs x (256x32)  [4096,20480) u16
  u16* A3s = sh;            // A3 slabs: 8 x (64x32) [0,16384) u16 (aliases As/Bs)
  u16* W4s = sh + 16384;    // W4 staging: 2 slabs x (128x32) [16384,24576) u16
  // blend tile 64x136 aliases sh[0,8704) after layer-4.

  const int tid = threadIdx.x;
  const int w = tid >> 6;
  const int lane = tid & 63;
  const int nmt = M >> 6;
  int bm;
  if ((nmt & 7) == 0) bm = (blockIdx.x & 7) * (nmt >> 3) + (blockIdx.x >> 3);
  else bm = blockIdx.x;
  const int m0 = bm << 6;

  const int lrow = tid >> 2;                 // 0..63
  const int cc   = tid & 3;
  const int gcol = (cc ^ ((lrow >> 1) & 3)) << 3;

  const int fr = lane & 15;
  const int fq = lane >> 4;
  const int rchunk = (fq ^ ((fr >> 1) & 3)) << 3;
  const int nb3 = w << 6;                    // layer-3 wave col base

  // ---------------- layer-3 (M-tile 64, N 256, K 512) ----------------
  f32x4 acc3[4][4];
#pragma unroll
  for (int ii = 0; ii < 4; ++ii)
#pragma unroll
    for (int jj = 0; jj < 4; ++jj)
      acc3[ii][jj] = f32x4{0.f, 0.f, 0.f, 0.f};

  for (int kt = 0; kt < 512; kt += 64) {
#pragma unroll
    for (int s = 0; s < 2; ++s) {
      const int kb = kt + (s << 5);
      gload_lds16(A2 + (size_t)(m0 + lrow) * 512 + (kb + gcol),
                  (char*)As + (s << 12) + (w << 10));
#pragma unroll
      for (int q = 0; q < 4; ++q) {
        gload_lds16(W3T + (size_t)((q << 6) + lrow) * 512 + (kb + gcol),
                    (char*)Bs + (s << 14) + (q << 12) + (w << 10));
      }
    }
    __syncthreads();
#pragma unroll
    for (int s = 0; s < 2; ++s) {
      bf16x8 af[4], bfv[4];
#pragma unroll
      for (int ii = 0; ii < 4; ++ii) {
        af[ii]  = *(const bf16x8*)(As + (s << 11) + (((ii << 4) + fr) << 5) + rchunk);
        bfv[ii] = *(const bf16x8*)(Bs + (s << 13) + ((nb3 + (ii << 4) + fr) << 5) + rchunk);
      }
#pragma unroll
      for (int ii = 0; ii < 4; ++ii)
#pragma unroll
        for (int jj = 0; jj < 4; ++jj)
          acc3[ii][jj] = __builtin_amdgcn_mfma_f32_16x16x32_bf16(af[ii], bfv[jj], acc3[ii][jj], 0, 0, 0);
    }
    __syncthreads();
  }

  // ---------------- funnel: A3 = relu(acc3+b3) -> swizzled LDS slabs -------
  float b3v[4];
#pragma unroll
  for (int jj = 0; jj < 4; ++jj) b3v[jj] = b3[nb3 + (jj << 4) + fr];
#pragma unroll
  for (int jj = 0; jj < 4; ++jj) {
    const int col = nb3 + (jj << 4) + fr;
    const int sl = col >> 5, c = col & 31;
#pragma unroll
    for (int ii = 0; ii < 4; ++ii) {
#pragma unroll
      for (int r = 0; r < 4; ++r) {
        const int row = (ii << 4) + (fq << 2) + r;
        A3s[(sl << 11) + (row << 5) + (((c >> 3) ^ ((row >> 1) & 3)) << 3) + (c & 7)] =
            f2bf(fmaxf(acc3[ii][jj][r] + b3v[jj], 0.f));
      }
    }
  }

  // ---------------- layer-4 (K=256 from A3 slabs; N=128) ----------------
  f32x4 acc4[4][2];
#pragma unroll
  for (int ii = 0; ii < 4; ++ii)
#pragma unroll
    for (int jj = 0; jj < 2; ++jj)
      acc4[ii][jj] = f32x4{0.f, 0.f, 0.f, 0.f};
  const int nb4 = w << 5;

  for (int kt4 = 0; kt4 < 4; ++kt4) {
#pragma unroll
    for (int s = 0; s < 2; ++s) {
      const int kb = (kt4 << 6) + (s << 5);
#pragma unroll
      for (int q = 0; q < 2; ++q) {
        gload_lds16(W4T + (size_t)((q << 6) + lrow) * 256 + (kb + gcol),
                    (char*)W4s + (s << 13) + (q << 12) + (w << 10));
      }
    }
    __syncthreads();   // W4 visible; first iter also publishes the A3 funnel
#pragma unroll
    for (int s = 0; s < 2; ++s) {
      const int sl = (kt4 << 1) + s;
      bf16x8 af[4], bfv[2];
#pragma unroll
      for (int ii = 0; ii < 4; ++ii)
        af[ii] = *(const bf16x8*)(A3s + (sl << 11) + (((ii << 4) + fr) << 5) + rchunk);
#pragma unroll
      for (int jj = 0; jj < 2; ++jj)
        bfv[jj] = *(const bf16x8*)(W4s + (s << 12) + ((nb4 + (jj << 4) + fr) << 5) + rchunk);
#pragma unroll
      for (int ii = 0; ii < 4; ++ii)
#pragma unroll
        for (int jj = 0; jj < 2; ++jj)
          acc4[ii][jj] = __builtin_amdgcn_mfma_f32_16x16x32_bf16(af[ii], bfv[jj], acc4[ii][jj], 0, 0, 0);
    }
    __syncthreads();
  }

  // ---------------- layer-5 + softmax blend ----------------
  float b4v[2];
#pragma unroll
  for (int jj = 0; jj < 2; ++jj) b4v[jj] = b4[nb4 + (jj << 4) + fr];
#pragma unroll
  for (int ii = 0; ii < 4; ++ii) {
#pragma unroll
    for (int jj = 0; jj < 2; ++jj) {
      const int col = nb4 + (jj << 4) + fr;
#pragma unroll
      for (int r = 0; r < 4; ++r) {
        const int row = (ii << 4) + (fq << 2) + r;
        sh[row * 136 + col] = f2bf(fmaxf(acc4[ii][jj][r] + b4v[jj], 0.f));
      }
    }
  }
  const int cbase = fr << 3;
  float w50[8], w51[8];
#pragma unroll
  for (int j = 0; j < 8; ++j) {
    w50[j] = w5[((cbase + j) << 1) + 0];
    w51[j] = w5[((cbase + j) << 1) + 1];
  }
  const float b50 = b5[0], b51 = b5[1];
  __syncthreads();

#pragma unroll
  for (int rep = 0; rep < 4; ++rep) {
    const int pl = (rep << 2) + w;            // block-local pixel 0..15
    const int row = (pl << 2) + fq;           // branch k = fq
    const u16x8 v = *(const u16x8*)(sh + row * 136 + cbase);
    float s0 = 0.f, s1 = 0.f;
#pragma unroll
    for (int j = 0; j < 8; ++j) {
      const float a = bf2f(v[j]);
      s0 += a * w50[j];
      s1 += a * w51[j];
    }
#pragma unroll
    for (int off = 8; off >= 1; off >>= 1) {
      s0 += __shfl_xor(s0, off, 16);
      s1 += __shfl_xor(s1, off, 16);
    }
    float p0[4], p1[4];
#pragma unroll
    for (int k = 0; k < 4; ++k) {
      p0[k] = __shfl(s0, k << 4, 64) + b50;
      p1[k] = __shfl(s1, k << 4, 64) + b51;
    }
    if (lane == 0) {
      float mx = fmaxf(fmaxf(p1[0], p1[1]), fmaxf(p1[2], p1[3]));
      float e0 = expf(p1[0] - mx), e1 = expf(p1[1] - mx);
      float e2 = expf(p1[2] - mx), e3 = expf(p1[3] - mx);
      outp[gp0 + (m0 >> 2) + pl] =
          (p0[0] * e0 + p0[1] * e1 + p0[2] * e2 + p0[3] * e3) / (e0 + e1 + e2 + e3);
    }
  }
}

// ---------------------------------------------------------------------------
// prep_all: all transposed bf16 weights in one dispatch (+ bf16 w1rel).
// ---------------------------------------------------------------------------
__global__ __launch_bounds__(256)
void prep_all(const float* __restrict__ w1, const float* __restrict__ w2,
              const float* __restrict__ w3, const float* __restrict__ w4,
              u16* __restrict__ W1hrT, u16* __restrict__ W1cellT,
              u16* __restrict__ W2T, u16* __restrict__ W3T, u16* __restrict__ W4T,
              u16* __restrict__ W1rb)
{
  const int idx = blockIdx.x * 256 + threadIdx.x;
  if (idx < 131072) {
    const int n = idx >> 7, k = idx & 127;
    W1hrT[idx] = f2bf(w1[(128 + k) * 1024 + n] + w1[(256 + k) * 1024 + n]);
  } else if (idx < 393216) {
    const int i = idx - 131072;
    const int n = i >> 8, k = i & 255;
    W1cellT[i] = f2bf((k < 128) ? w1[k * 1024 + n] : w1[(128 + k) * 1024 + n]);
  } else if (idx < 917504) {
    const int i = idx - 393216;
    const int n = i >> 10, k = i & 1023;
    W2T[i] = f2bf(w2[k * 512 + n]);
  } else if (idx < 1048576) {
    const int i = idx - 917504;
    const int n = i >> 9, k = i & 511;
    W3T[i] = f2bf(w3[k * 256 + n]);
  } else if (idx < 1081344) {
    const int i = idx - 1048576;
    const int n = i >> 8, k = i & 255;
    W4T[i] = f2bf(w4[k * 128 + n]);
  } else if (idx < 1083392) {
    const int i = idx - 1081344;
    W1rb[i] = f2bf(w1[384 * 1024 + i]);      // w1rel rows 384,385 -> bf16
  }
}

// ---------------------------------------------------------------------------
extern "C" void kernel_launch(void* const* d_in, const int* in_sizes, int n_in,
                              void* d_out, int out_size, void* d_ws, size_t ws_size,
                              hipStream_t stream)
{
  const float* feat  = (const float*)d_in[0];
  const float* coord = (const float*)d_in[1];
  const float* hrg   = (const float*)d_in[2];
  const float* lrg   = (const float*)d_in[3];
  const float* w1 = (const float*)d_in[4];
  const float* b1 = (const float*)d_in[5];
  const float* w2 = (const float*)d_in[6];
  const float* b2 = (const float*)d_in[7];
  const float* w3 = (const float*)d_in[8];
  const float* b3 = (const float*)d_in[9];
  const float* w4 = (const float*)d_in[10];
  const float* b4 = (const float*)d_in[11];
  const float* w5 = (const float*)d_in[12];
  const float* b5 = (const float*)d_in[13];
  float* out = (float*)d_out;

  char* base = (char*)d_ws;
  u16* W1hrT   = (u16*)base;                       // [1024][128]
  u16* W1cellT = W1hrT + 1024 * 128;               // [1024][256]
  u16* W2T     = W1cellT + 1024 * 256;             // [512][1024]
  u16* W3T     = W2T + 512 * 1024;                 // [256][512]
  u16* W4T     = W3T + 256 * 512;                  // [128][256]
  u16* W1rb    = W4T + 128 * 256;                  // [2][1024] bf16 w1rel
  u16* Xcell   = W1rb + 2048;                      // [8192][256]
  u16* Ycell   = Xcell + 8192 * 256;               // [8192][1024] bf16
  u16* Xhr     = Ycell + (size_t)8192 * 1024;      // [131072][128]
  float* relb  = (float*)(Xhr + (size_t)131072 * 128); // [131072][4][2]
  int* cellidx = (int*)(relb + (size_t)131072 * 8);    // [131072][4]
  char* chunk_base = (char*)(cellidx + (size_t)131072 * 4);
  const size_t fixed = (size_t)(chunk_base - base);

  const int NP = 131072;
  // per-pixel chunk bytes: Yhr 2048 + A2 4096 = 6144 (A1 fused away)
  int nc = 1;
  while (nc < 128 && fixed + (size_t)(NP / nc) * 6144ULL > ws_size) nc <<= 1;
  const int CP = NP / nc;
  const int R = CP * 4;

  u16* Yhr = (u16*)chunk_base;          // [CP][1024] bf16 (Yhr + b1 folded)
  u16* A2  = Yhr + (size_t)CP * 1024;   // [R][512] bf16

  prep_all<<<4232, 256, 0, stream>>>(w1, w2, w3, w4, W1hrT, W1cellT, W2T, W3T,
                                     W4T, W1rb);
  gather_hr<<<NP / 64, 256, 0, stream>>>(coord, hrg, Xhr, cellidx, relb);
  prep_cells<<<8192 / 64, 256, 0, stream>>>(feat, lrg, Xcell);
  // Ycell = Xcell @ W1cellT^T (raw bf16)
  gemm_bt<3><<<(8192 / 128) * (1024 / 128), 256, 0, stream>>>(
      Xcell, W1cellT, (void*)Ycell, nullptr, 8192, 1024, 256);

  for (int ch = 0; ch < nc; ++ch) {
    const int gp0 = ch * CP;
    // Yhrb = Xhr_chunk @ W1hrT^T + b1 (MODE 1: bias, no relu)
    gemm_bt<1><<<(CP / 128) * (1024 / 128), 256, 0, stream>>>(
        Xhr + (size_t)gp0 * 128, W1hrT, (void*)Yhr, b1, CP, 1024, 128);
    // fused expand + layer-2: A2 = relu(A1(Yhrb,Ycell,rel) @ W2T^T + b2)
    gemm_l12<<<(R >> 7), 512, 0, stream>>>(
        Yhr, Ycell, W1rb, cellidx, relb, W2T, A2, b2, R, 1024, gp0);
    tail34<<<R / 64, 256, 0, stream>>>(
        A2, W3T, W4T, b3, b4, w5, b5, out, R, gp0);
  }
}